// Round 1
// baseline (3233.279 us; speedup 1.0000x reference)
//
#include <hip/hip_runtime.h>
#include <math.h>

static constexpr int Bn = 4, Tlen = 2048, Cdim = 1024, Hn = 16, Dh = 64;
static constexpr int Mtot = Bn * Tlen;

// C[m,n] = sum_k A[m,k]*B[n,k] + bias[n]   (NT GEMM, both row-major over k)
__global__ __launch_bounds__(256) void gemm_nt(const float* __restrict__ A,
                                               const float* __restrict__ B,
                                               const float* __restrict__ bias,
                                               float* __restrict__ C,
                                               int M, int N, int K)
{
    __shared__ float As[16][68];   // [k][row], padded
    __shared__ float Bs[16][68];
    const int tid = threadIdx.x;
    const int m0 = blockIdx.x * 64;
    const int n0 = blockIdx.y * 64;
    const int ty = tid >> 4, tx = tid & 15;
    const int lrow = tid >> 2;            // 0..63
    const int lk4  = (tid & 3) << 2;      // 0,4,8,12

    float acc[4][4] = {};
    for (int k0 = 0; k0 < K; k0 += 16) {
        float4 av = *(const float4*)(A + (size_t)(m0 + lrow) * K + k0 + lk4);
        float4 bv = *(const float4*)(B + (size_t)(n0 + lrow) * K + k0 + lk4);
        As[lk4 + 0][lrow] = av.x; As[lk4 + 1][lrow] = av.y;
        As[lk4 + 2][lrow] = av.z; As[lk4 + 3][lrow] = av.w;
        Bs[lk4 + 0][lrow] = bv.x; Bs[lk4 + 1][lrow] = bv.y;
        Bs[lk4 + 2][lrow] = bv.z; Bs[lk4 + 3][lrow] = bv.w;
        __syncthreads();
#pragma unroll
        for (int kk = 0; kk < 16; ++kk) {
            float4 a4 = *(const float4*)&As[kk][ty << 2];
            float4 b4 = *(const float4*)&Bs[kk][tx << 2];
            float a[4] = {a4.x, a4.y, a4.z, a4.w};
            float b[4] = {b4.x, b4.y, b4.z, b4.w};
#pragma unroll
            for (int i = 0; i < 4; ++i)
#pragma unroll
                for (int j = 0; j < 4; ++j)
                    acc[i][j] = fmaf(a[i], b[j], acc[i][j]);
        }
        __syncthreads();
    }
    float4 b4 = *(const float4*)(bias + n0 + (tx << 2));
    float bb[4] = {b4.x, b4.y, b4.z, b4.w};
#pragma unroll
    for (int i = 0; i < 4; ++i) {
        float4 o;
        o.x = acc[i][0] + bb[0]; o.y = acc[i][1] + bb[1];
        o.z = acc[i][2] + bb[2]; o.w = acc[i][3] + bb[3];
        *(float4*)(C + (size_t)(m0 + (ty << 2) + i) * N + n0 + (tx << 2)) = o;
    }
}

// Flash attention, causal, fp32. One block per (b, h, 64-row q tile).
// q,k,v,y layout: [B, T, H*D] (head h at column h*64). y may alias q
// (each block writes only the q rows/cols it alone read) -> no __restrict__.
__global__ __launch_bounds__(256) void attn_fp32(const float* q,
                                                 const float* __restrict__ k,
                                                 const float* __restrict__ v,
                                                 float* y)
{
    const int qt = blockIdx.x, h = blockIdx.y, b = blockIdx.z;
    const int tid = threadIdx.x;
    __shared__ float Qs[64][68];
    __shared__ float Ks[32][68];
    __shared__ float Vs[32][68];
    __shared__ float Ps[64][33];

    const int q0 = qt * 64;
    const float* qbase = q + ((size_t)(b * Tlen + q0)) * Cdim + h * Dh;
#pragma unroll
    for (int i = 0; i < 4; ++i) {
        int fid = tid + i * 256;           // 0..1023
        int r = fid >> 4;
        int c4 = (fid & 15) << 2;
        *(float4*)&Qs[r][c4] = *(const float4*)(qbase + (size_t)r * Cdim + c4);
    }

    const int ty = tid >> 4;   // 0..15 (row group)
    const int tx = tid & 15;   // 0..15
    const int r0 = ty << 2;    // 4 rows per thread
    const int c0s = tx << 1;   // 2 S-cols per thread (KB=32)
    const int c0o = tx << 2;   // 4 O-cols per thread (D=64)

    float m_i[4], l_i[4], acc[4][4];
#pragma unroll
    for (int i = 0; i < 4; ++i) {
        m_i[i] = -INFINITY; l_i[i] = 0.f;
#pragma unroll
        for (int j = 0; j < 4; ++j) acc[i][j] = 0.f;
    }

    const int jmax = 2 * qt + 1;           // kv tiles of 32 with any col <= q0+63
    for (int jt = 0; jt <= jmax; ++jt) {
        __syncthreads();                   // prev PV done before K/V overwrite
        const float* kbase = k + ((size_t)(b * Tlen + jt * 32)) * Cdim + h * Dh;
        const float* vbase = v + ((size_t)(b * Tlen + jt * 32)) * Cdim + h * Dh;
#pragma unroll
        for (int i = 0; i < 2; ++i) {
            int fid = tid + i * 256;       // 0..511
            int r = fid >> 4;
            int c4 = (fid & 15) << 2;
            *(float4*)&Ks[r][c4] = *(const float4*)(kbase + (size_t)r * Cdim + c4);
            *(float4*)&Vs[r][c4] = *(const float4*)(vbase + (size_t)r * Cdim + c4);
        }
        __syncthreads();

        // S = Q K^T (thread: 4 rows x 2 cols)
        float s[4][2] = {};
        for (int d = 0; d < 64; ++d) {
            float kv0 = Ks[c0s][d], kv1 = Ks[c0s + 1][d];
#pragma unroll
            for (int i = 0; i < 4; ++i) {
                float qv = Qs[r0 + i][d];
                s[i][0] = fmaf(qv, kv0, s[i][0]);
                s[i][1] = fmaf(qv, kv1, s[i][1]);
            }
        }
        // causal mask + 1/sqrt(D)
#pragma unroll
        for (int i = 0; i < 4; ++i) {
            int gq = q0 + r0 + i;
#pragma unroll
            for (int j = 0; j < 2; ++j) {
                int gk = jt * 32 + c0s + j;
                s[i][j] = (gk <= gq) ? s[i][j] * 0.125f : -INFINITY;
            }
        }
        // online softmax update (per-row reduce over the 16 tx lanes)
#pragma unroll
        for (int i = 0; i < 4; ++i) {
            float rmax = fmaxf(s[i][0], s[i][1]);
#pragma unroll
            for (int off = 1; off < 16; off <<= 1)
                rmax = fmaxf(rmax, __shfl_xor(rmax, off, 16));
            float newm = fmaxf(m_i[i], rmax);
            float sc = __expf(m_i[i] - newm);   // 0 on first tile, 1 on all-masked tile
            float p0 = __expf(s[i][0] - newm);
            float p1 = __expf(s[i][1] - newm);
            float rsum = p0 + p1;
#pragma unroll
            for (int off = 1; off < 16; off <<= 1)
                rsum += __shfl_xor(rsum, off, 16);
            m_i[i] = newm;
            l_i[i] = l_i[i] * sc + rsum;
#pragma unroll
            for (int j = 0; j < 4; ++j) acc[i][j] *= sc;
            Ps[r0 + i][c0s]     = p0;
            Ps[r0 + i][c0s + 1] = p1;
        }
        __syncthreads();
        // O += P @ V (thread: 4 rows x 4 cols)
        for (int s2 = 0; s2 < 32; ++s2) {
            float vv[4];
#pragma unroll
            for (int j = 0; j < 4; ++j) vv[j] = Vs[s2][c0o + j];
#pragma unroll
            for (int i = 0; i < 4; ++i) {
                float pp = Ps[r0 + i][s2];
#pragma unroll
                for (int j = 0; j < 4; ++j)
                    acc[i][j] = fmaf(pp, vv[j], acc[i][j]);
            }
        }
    }

    float* ybase = y + ((size_t)(b * Tlen + q0)) * Cdim + h * Dh;
#pragma unroll
    for (int i = 0; i < 4; ++i) {
        float inv = 1.f / l_i[i];
        float4 o;
        o.x = acc[i][0] * inv; o.y = acc[i][1] * inv;
        o.z = acc[i][2] * inv; o.w = acc[i][3] * inv;
        *(float4*)(ybase + (size_t)(r0 + i) * Cdim + c0o) = o;
    }
}

extern "C" void kernel_launch(void* const* d_in, const int* in_sizes, int n_in,
                              void* d_out, int out_size, void* d_ws, size_t ws_size,
                              hipStream_t stream) {
    const float* x  = (const float*)d_in[0];
    const float* Wq = (const float*)d_in[1];
    const float* bq = (const float*)d_in[2];
    const float* Wk = (const float*)d_in[3];
    const float* bk = (const float*)d_in[4];
    const float* Wv = (const float*)d_in[5];
    const float* bv = (const float*)d_in[6];
    const float* Wp = (const float*)d_in[7];
    const float* bp = (const float*)d_in[8];
    float* out = (float*)d_out;

    float* ws = (float*)d_ws;
    const size_t plane = (size_t)Mtot * Cdim;   // 8M floats = 32 MiB
    float* qbuf = ws;                           // later reused as y (in-place)
    float* kbuf = ws + plane;
    float* vbuf = ws + 2 * plane;               // total ws use: 96 MiB

    dim3 ggrid(Mtot / 64, Cdim / 64);
    gemm_nt<<<ggrid, 256, 0, stream>>>(x, Wq, bq, qbuf, Mtot, Cdim, Cdim);
    gemm_nt<<<ggrid, 256, 0, stream>>>(x, Wk, bk, kbuf, Mtot, Cdim, Cdim);
    gemm_nt<<<ggrid, 256, 0, stream>>>(x, Wv, bv, vbuf, Mtot, Cdim, Cdim);

    attn_fp32<<<dim3(Tlen / 64, Hn, Bn), 256, 0, stream>>>(qbuf, kbuf, vbuf, qbuf);

    gemm_nt<<<ggrid, 256, 0, stream>>>(qbuf, Wp, bp, out, Mtot, Cdim, Cdim);
}

// Round 2
// 362.805 us; speedup vs baseline: 8.9119x; 8.9119x over previous
//
#include <hip/hip_runtime.h>
#include <math.h>

static constexpr int Bn = 4, Tlen = 2048, Cdim = 1024, Hn = 16, Dh = 64;
static constexpr int Mtot = Bn * Tlen;

typedef __attribute__((ext_vector_type(8))) short   s16x8;
typedef __attribute__((ext_vector_type(4))) float   f32x4;
typedef unsigned short u16;

__device__ __forceinline__ u16 f2bf(float f) {
    union { float f; unsigned u; } x; x.f = f;
    unsigned r = x.u + 0x7FFFu + ((x.u >> 16) & 1u);   // RNE
    return (u16)(r >> 16);
}

__device__ __forceinline__ void gload_lds16(const void* g, void* l) {
    __builtin_amdgcn_global_load_lds(
        (const __attribute__((address_space(1))) void*)g,
        (__attribute__((address_space(3))) void*)l, 16, 0, 0);
}

// ---------------- fp32 -> bf16 convert (vectorized) ----------------
__global__ __launch_bounds__(256) void cvt_bf16(const float* __restrict__ in,
                                                u16* __restrict__ out) {
    size_t i = (size_t)(blockIdx.x * 256 + threadIdx.x) * 8;
    float4 a = *(const float4*)(in + i);
    float4 b = *(const float4*)(in + i + 4);
    s16x8 o;
    o[0] = (short)f2bf(a.x); o[1] = (short)f2bf(a.y);
    o[2] = (short)f2bf(a.z); o[3] = (short)f2bf(a.w);
    o[4] = (short)f2bf(b.x); o[5] = (short)f2bf(b.y);
    o[6] = (short)f2bf(b.z); o[7] = (short)f2bf(b.w);
    *(s16x8*)(out + i) = o;
}

// ---------------- bf16 NT GEMM, m97-style 128x128, BK=32 ----------------
// C[m,n] = sum_k A[m,k]*B[n,k] + bias[n]
template <int BF16OUT>
__global__ __launch_bounds__(256) void gemm_nt_bf16(const u16* __restrict__ A,
                                                    const u16* __restrict__ B,
                                                    const float* __restrict__ bias,
                                                    void* __restrict__ Cout,
                                                    int M, int N, int K) {
    __shared__ u16 As[128 * 32];   // [row][k] linear; granule = row*4 + k16
    __shared__ u16 Bs[128 * 32];
    const int tid = threadIdx.x, lane = tid & 63, w = tid >> 6;
    const int m0 = blockIdx.x * 128, n0 = blockIdx.y * 128;
    const int wm = w >> 1, wn = w & 1;
    const int rowA = lane & 15, kg = lane >> 4;
    const int srow = lane >> 2, sc = (lane & 3) * 8;

    f32x4 acc[4][4] = {};
    const u16* Abase = A + (size_t)m0 * K;
    const u16* Bbase = B + (size_t)n0 * K;

    for (int k0 = 0; k0 < K; k0 += 32) {
        __syncthreads();                       // prior reads done
#pragma unroll
        for (int i = 0; i < 2; ++i) {          // wave stages 32 rows of A and B
            int r0 = w * 32 + i * 16;
            gload_lds16(Abase + (size_t)(r0 + srow) * K + k0 + sc, As + r0 * 32);
            gload_lds16(Bbase + (size_t)(r0 + srow) * K + k0 + sc, Bs + r0 * 32);
        }
        asm volatile("s_waitcnt vmcnt(0)" ::: "memory");
        __syncthreads();

        s16x8 af[4], bfr[4];
#pragma unroll
        for (int mf = 0; mf < 4; ++mf)
            af[mf] = *(const s16x8*)&As[(wm * 64 + mf * 16 + rowA) * 32 + kg * 8];
#pragma unroll
        for (int nf = 0; nf < 4; ++nf)
            bfr[nf] = *(const s16x8*)&Bs[(wn * 64 + nf * 16 + rowA) * 32 + kg * 8];
#pragma unroll
        for (int mf = 0; mf < 4; ++mf)
#pragma unroll
            for (int nf = 0; nf < 4; ++nf)
                acc[mf][nf] = __builtin_amdgcn_mfma_f32_16x16x32_bf16(
                    af[mf], bfr[nf], acc[mf][nf], 0, 0, 0);
    }

    float bb[4];
#pragma unroll
    for (int nf = 0; nf < 4; ++nf) bb[nf] = bias[n0 + wn * 64 + nf * 16 + rowA];
#pragma unroll
    for (int mf = 0; mf < 4; ++mf)
#pragma unroll
        for (int nf = 0; nf < 4; ++nf)
#pragma unroll
            for (int r = 0; r < 4; ++r) {
                float val = acc[mf][nf][r] + bb[nf];
                size_t row = m0 + wm * 64 + mf * 16 + kg * 4 + r;
                size_t col = n0 + wn * 64 + nf * 16 + rowA;
                if (BF16OUT) ((u16*)Cout)[row * N + col] = f2bf(val);
                else         ((float*)Cout)[row * N + col] = val;
            }
}

// ---------------- V transpose: [B,T,H,D] bf16 -> [B,H,D,T] bf16 ----------------
__global__ __launch_bounds__(256) void transpose_v(const u16* __restrict__ v,
                                                   u16* __restrict__ vt) {
    __shared__ u16 tile[64][72];
    const int tid = threadIdx.x;
    const int t0 = blockIdx.x * 64, bh = blockIdx.y;
    const u16* src = v + ((size_t)((bh >> 4) * Tlen + t0)) * Cdim + (bh & 15) * Dh;
#pragma unroll
    for (int i = 0; i < 2; ++i) {
        int ch = tid + i * 256, t = ch >> 3, c = (ch & 7) * 8;
        *(s16x8*)&tile[t][c] = *(const s16x8*)(src + (size_t)t * Cdim + c);
    }
    __syncthreads();
    u16* dst = vt + ((size_t)bh * Dh) * Tlen + t0;
#pragma unroll
    for (int i = 0; i < 2; ++i) {
        int ch = tid + i * 256, d = ch >> 3, tt = (ch & 7) * 8;
        s16x8 o;
#pragma unroll
        for (int j = 0; j < 8; ++j) o[j] = (short)tile[tt + j][d];
        *(s16x8*)(dst + (size_t)d * Tlen + tt) = o;
    }
}

// ---------------- MFMA flash attention (causal), bf16 in/out ----------------
// q,k: [B,T,C] bf16; vt: [B,H,D,T] bf16; y: [B,T,C] bf16 (may alias q).
// Block = (qtile, h, b); 4 waves, wave w owns q rows [w*16, w*16+16).
__global__ __launch_bounds__(256) void attn_mfma(const u16* __restrict__ q,
                                                 const u16* __restrict__ k,
                                                 const u16* __restrict__ vt,
                                                 u16* y) {
    const int qt = blockIdx.x, h = blockIdx.y, b = blockIdx.z;
    const int tid = threadIdx.x, lane = tid & 63, w = tid >> 6;
    __shared__ u16 Qs[64 * 64], Ks[64 * 64], Vts[64 * 64];  // XOR-swizzled rows
    __shared__ u16 Ps[4][16 * 64];                          // per-wave P, swizzled

    const int q0 = qt * 64;
    const int rowA = lane & 15, kg = lane >> 4;
    const int srow8 = lane >> 3, scol8 = lane & 7;

    // stage Q (pre-swizzled global source -> linear LDS == swizzled layout)
    const u16* qbase = q + ((size_t)(b * Tlen + q0)) * Cdim + h * Dh;
#pragma unroll
    for (int i = 0; i < 2; ++i) {
        int r0 = w * 16 + i * 8;
        int row = r0 + srow8;
        gload_lds16(qbase + (size_t)row * Cdim + (scol8 ^ (row & 7)) * 8, Qs + r0 * 64);
    }

    f32x4 acc[4] = {};
    float m_i[4], l_i[4];
#pragma unroll
    for (int r = 0; r < 4; ++r) { m_i[r] = -INFINITY; l_i[r] = 0.f; }

    for (int jt = 0; jt <= qt; ++jt) {
        __syncthreads();   // prev PV reads done before K/V overwrite
        const u16* kbase = k + ((size_t)(b * Tlen + jt * 64)) * Cdim + h * Dh;
        const u16* vtbase = vt + ((size_t)(b * Hn + h)) * Dh * Tlen + jt * 64;
#pragma unroll
        for (int i = 0; i < 2; ++i) {
            int r0 = w * 16 + i * 8;
            int row = r0 + srow8;
            gload_lds16(kbase + (size_t)row * Cdim + (scol8 ^ (row & 7)) * 8, Ks + r0 * 64);
            gload_lds16(vtbase + (size_t)row * Tlen + (scol8 ^ (row & 7)) * 8, Vts + r0 * 64);
        }
        asm volatile("s_waitcnt vmcnt(0)" ::: "memory");
        __syncthreads();

        // S = Q K^T : wave computes 16 rows x 64 keys
        f32x4 sf[4] = {};
        const int qrow = w * 16 + rowA;
#pragma unroll
        for (int ks = 0; ks < 2; ++ks) {
            s16x8 a = *(const s16x8*)&Qs[qrow * 64 + ((ks * 32 + kg * 8) ^ ((qrow & 7) << 3))];
#pragma unroll
            for (int f = 0; f < 4; ++f) {
                int krow = f * 16 + rowA;
                s16x8 bb = *(const s16x8*)&Ks[krow * 64 + ((ks * 32 + kg * 8) ^ ((krow & 7) << 3))];
                sf[f] = __builtin_amdgcn_mfma_f32_16x16x32_bf16(a, bb, sf[f], 0, 0, 0);
            }
        }
        // scale + causal mask (diagonal tile only)
        const bool diag = (jt == qt);
#pragma unroll
        for (int f = 0; f < 4; ++f)
#pragma unroll
            for (int r = 0; r < 4; ++r) {
                float sv = sf[f][r] * 0.125f;
                if (diag) {
                    int kglob = jt * 64 + f * 16 + rowA;       // C/D col = lane&15
                    int qglob = q0 + w * 16 + kg * 4 + r;      // C/D row
                    if (kglob > qglob) sv = -INFINITY;
                }
                sf[f][r] = sv;
            }
        // online softmax (rows owned: kg*4+r; reduce over 16 lanes of same kg)
#pragma unroll
        for (int r = 0; r < 4; ++r) {
            float rm = fmaxf(fmaxf(sf[0][r], sf[1][r]), fmaxf(sf[2][r], sf[3][r]));
#pragma unroll
            for (int off = 1; off < 16; off <<= 1) rm = fmaxf(rm, __shfl_xor(rm, off));
            float nm = fmaxf(m_i[r], rm);
            float sc = __expf(m_i[r] - nm);
            float rs = 0.f;
            const int prow = kg * 4 + r;
#pragma unroll
            for (int f = 0; f < 4; ++f) {
                float p = __expf(sf[f][r] - nm);
                rs += p;
                Ps[w][prow * 64 + ((f * 16 + rowA) ^ ((prow & 7) << 3))] = f2bf(p);
            }
#pragma unroll
            for (int off = 1; off < 16; off <<= 1) rs += __shfl_xor(rs, off);
            m_i[r] = nm;
            l_i[r] = l_i[r] * sc + rs;
#pragma unroll
            for (int db = 0; db < 4; ++db) acc[db][r] *= sc;
        }
        // O += P @ V
#pragma unroll
        for (int ks = 0; ks < 2; ++ks) {
            s16x8 pa = *(const s16x8*)&Ps[w][rowA * 64 + ((ks * 32 + kg * 8) ^ ((rowA & 7) << 3))];
#pragma unroll
            for (int db = 0; db < 4; ++db) {
                int vrow = db * 16 + rowA;
                s16x8 vb = *(const s16x8*)&Vts[vrow * 64 + ((ks * 32 + kg * 8) ^ ((vrow & 7) << 3))];
                acc[db] = __builtin_amdgcn_mfma_f32_16x16x32_bf16(pa, vb, acc[db], 0, 0, 0);
            }
        }
    }

    u16* ybase = y + ((size_t)(b * Tlen + q0 + w * 16)) * Cdim + h * Dh;
#pragma unroll
    for (int r = 0; r < 4; ++r) {
        float inv = 1.f / l_i[r];
#pragma unroll
        for (int db = 0; db < 4; ++db)
            ybase[(size_t)(kg * 4 + r) * Cdim + db * 16 + rowA] = f2bf(acc[db][r] * inv);
    }
}

extern "C" void kernel_launch(void* const* d_in, const int* in_sizes, int n_in,
                              void* d_out, int out_size, void* d_ws, size_t ws_size,
                              hipStream_t stream) {
    const float* x  = (const float*)d_in[0];
    const float* Wq = (const float*)d_in[1];
    const float* bq = (const float*)d_in[2];
    const float* Wk = (const float*)d_in[3];
    const float* bk = (const float*)d_in[4];
    const float* Wv = (const float*)d_in[5];
    const float* bv = (const float*)d_in[6];
    const float* Wp = (const float*)d_in[7];
    const float* bp = (const float*)d_in[8];
    float* out = (float*)d_out;

    const size_t plane = (size_t)Mtot * Cdim;   // 8M elems
    const size_t wsz   = (size_t)Cdim * Cdim;   // 1M elems
    u16* xb  = (u16*)d_ws;
    u16* wqb = xb + plane;
    u16* wkb = wqb + wsz;
    u16* wvb = wkb + wsz;
    u16* wpb = wvb + wsz;
    u16* qb  = wpb + wsz;
    u16* kb  = qb + plane;
    u16* vb  = kb + plane;
    u16* vtb = vb + plane;                      // total 88 MiB

    cvt_bf16<<<plane / 2048, 256, 0, stream>>>(x, xb);
    cvt_bf16<<<wsz / 2048, 256, 0, stream>>>(Wq, wqb);
    cvt_bf16<<<wsz / 2048, 256, 0, stream>>>(Wk, wkb);
    cvt_bf16<<<wsz / 2048, 256, 0, stream>>>(Wv, wvb);
    cvt_bf16<<<wsz / 2048, 256, 0, stream>>>(Wp, wpb);

    dim3 ggrid(Mtot / 128, Cdim / 128);
    gemm_nt_bf16<1><<<ggrid, 256, 0, stream>>>(xb, wqb, bq, qb, Mtot, Cdim, Cdim);
    gemm_nt_bf16<1><<<ggrid, 256, 0, stream>>>(xb, wkb, bk, kb, Mtot, Cdim, Cdim);
    gemm_nt_bf16<1><<<ggrid, 256, 0, stream>>>(xb, wvb, bv, vb, Mtot, Cdim, Cdim);

    transpose_v<<<dim3(Tlen / 64, Bn * Hn), 256, 0, stream>>>(vb, vtb);

    attn_mfma<<<dim3(Tlen / 64, Hn, Bn), 256, 0, stream>>>(qb, kb, vtb, qb);

    gemm_nt_bf16<0><<<ggrid, 256, 0, stream>>>(qb, wpb, bp, out, Mtot, Cdim, Cdim);
}

// Round 3
// 348.871 us; speedup vs baseline: 9.2678x; 1.0399x over previous
//
#include <hip/hip_runtime.h>
#include <hip/hip_bf16.h>
#include <math.h>

static constexpr int Bn = 4, Tlen = 2048, Cdim = 1024, Hn = 16, Dh = 64;
static constexpr int Mtot = Bn * Tlen;

typedef __attribute__((ext_vector_type(8))) short   s16x8;
typedef __attribute__((ext_vector_type(4))) float   f32x4;
typedef unsigned short u16;

// scale folded into Q: (1/sqrt(64)) * log2(e)
#define QSCALE 0.18033688011112042f

__device__ __forceinline__ u16 f2bf(float f) {
    union { float f; unsigned u; } x; x.f = f;
    unsigned r = x.u + 0x7FFFu + ((x.u >> 16) & 1u);   // RNE
    return (u16)(r >> 16);
}
__device__ __forceinline__ u16 cvt1(float f) {
    union { __hip_bfloat16 h; u16 u; } c; c.h = __float2bfloat16(f); return c.u;
}
__device__ __forceinline__ void gload_lds16(const void* g, void* l) {
    __builtin_amdgcn_global_load_lds(
        (const __attribute__((address_space(1))) void*)g,
        (__attribute__((address_space(3))) void*)l, 16, 0, 0);
}

// ---------------- fp32 -> bf16 convert (vectorized) ----------------
__global__ __launch_bounds__(256) void cvt_bf16(const float* __restrict__ in,
                                                u16* __restrict__ out) {
    size_t i = (size_t)(blockIdx.x * 256 + threadIdx.x) * 8;
    float4 a = *(const float4*)(in + i);
    float4 b = *(const float4*)(in + i + 4);
    s16x8 o;
    o[0] = (short)f2bf(a.x); o[1] = (short)f2bf(a.y);
    o[2] = (short)f2bf(a.z); o[3] = (short)f2bf(a.w);
    o[4] = (short)f2bf(b.x); o[5] = (short)f2bf(b.y);
    o[6] = (short)f2bf(b.z); o[7] = (short)f2bf(b.w);
    *(s16x8*)(out + i) = o;
}

// ---------------- fused QKV GEMM: A[8192,1024] x Wqkv[3072,1024]^T ----------------
// out planes (q,k,v) are contiguous at outbase + which*Mtot*Cdim, bf16.
// Q plane is additionally scaled by QSCALE (softmax scale folding).
__global__ __launch_bounds__(256) void gemm_qkv(const u16* __restrict__ A,
                                                const u16* __restrict__ B,
                                                const float* __restrict__ bq,
                                                const float* __restrict__ bk,
                                                const float* __restrict__ bv,
                                                u16* __restrict__ outbase) {
    constexpr int K = Cdim, N = Cdim;
    __shared__ u16 As[128 * 32];
    __shared__ u16 Bs[128 * 32];
    const int tid = threadIdx.x, lane = tid & 63, w = tid >> 6;
    const int m0 = blockIdx.x * 128, n0g = blockIdx.y * 128;
    const int which = n0g >> 10, n0 = n0g & 1023;
    const float* bias = which == 0 ? bq : (which == 1 ? bk : bv);
    const float osc = which == 0 ? QSCALE : 1.0f;
    u16* C = outbase + (size_t)which * ((size_t)Mtot * Cdim);
    const int wm = w >> 1, wn = w & 1;
    const int rowA = lane & 15, kg = lane >> 4;
    const int srow = lane >> 2, sc4 = (lane & 3) * 8;

    f32x4 acc[4][4] = {};
    const u16* Abase = A + (size_t)m0 * K;
    const u16* Bbase = B + (size_t)n0g * K;

    for (int k0 = 0; k0 < K; k0 += 32) {
        __syncthreads();
#pragma unroll
        for (int i = 0; i < 2; ++i) {
            int r0 = w * 32 + i * 16;
            gload_lds16(Abase + (size_t)(r0 + srow) * K + k0 + sc4, As + r0 * 32);
            gload_lds16(Bbase + (size_t)(r0 + srow) * K + k0 + sc4, Bs + r0 * 32);
        }
        asm volatile("s_waitcnt vmcnt(0)" ::: "memory");
        __syncthreads();

        s16x8 af[4], bfr[4];
#pragma unroll
        for (int mf = 0; mf < 4; ++mf)
            af[mf] = *(const s16x8*)&As[(wm * 64 + mf * 16 + rowA) * 32 + kg * 8];
#pragma unroll
        for (int nf = 0; nf < 4; ++nf)
            bfr[nf] = *(const s16x8*)&Bs[(wn * 64 + nf * 16 + rowA) * 32 + kg * 8];
#pragma unroll
        for (int mf = 0; mf < 4; ++mf)
#pragma unroll
            for (int nf = 0; nf < 4; ++nf)
                acc[mf][nf] = __builtin_amdgcn_mfma_f32_16x16x32_bf16(
                    af[mf], bfr[nf], acc[mf][nf], 0, 0, 0);
    }

    float bb[4];
#pragma unroll
    for (int nf = 0; nf < 4; ++nf) bb[nf] = bias[n0 + wn * 64 + nf * 16 + rowA];
#pragma unroll
    for (int mf = 0; mf < 4; ++mf)
#pragma unroll
        for (int nf = 0; nf < 4; ++nf)
#pragma unroll
            for (int r = 0; r < 4; ++r) {
                float val = (acc[mf][nf][r] + bb[nf]) * osc;
                size_t row = m0 + wm * 64 + mf * 16 + kg * 4 + r;
                size_t col = n0 + wn * 64 + nf * 16 + rowA;
                C[row * N + col] = f2bf(val);
            }
}

// ---------------- out-proj GEMM: bf16 A,B -> fp32 out ----------------
__global__ __launch_bounds__(256) void gemm_proj(const u16* __restrict__ A,
                                                 const u16* __restrict__ B,
                                                 const float* __restrict__ bias,
                                                 float* __restrict__ C) {
    constexpr int K = Cdim, N = Cdim;
    __shared__ u16 As[128 * 32];
    __shared__ u16 Bs[128 * 32];
    const int tid = threadIdx.x, lane = tid & 63, w = tid >> 6;
    const int m0 = blockIdx.x * 128, n0 = blockIdx.y * 128;
    const int wm = w >> 1, wn = w & 1;
    const int rowA = lane & 15, kg = lane >> 4;
    const int srow = lane >> 2, sc4 = (lane & 3) * 8;

    f32x4 acc[4][4] = {};
    const u16* Abase = A + (size_t)m0 * K;
    const u16* Bbase = B + (size_t)n0 * K;

    for (int k0 = 0; k0 < K; k0 += 32) {
        __syncthreads();
#pragma unroll
        for (int i = 0; i < 2; ++i) {
            int r0 = w * 32 + i * 16;
            gload_lds16(Abase + (size_t)(r0 + srow) * K + k0 + sc4, As + r0 * 32);
            gload_lds16(Bbase + (size_t)(r0 + srow) * K + k0 + sc4, Bs + r0 * 32);
        }
        asm volatile("s_waitcnt vmcnt(0)" ::: "memory");
        __syncthreads();

        s16x8 af[4], bfr[4];
#pragma unroll
        for (int mf = 0; mf < 4; ++mf)
            af[mf] = *(const s16x8*)&As[(wm * 64 + mf * 16 + rowA) * 32 + kg * 8];
#pragma unroll
        for (int nf = 0; nf < 4; ++nf)
            bfr[nf] = *(const s16x8*)&Bs[(wn * 64 + nf * 16 + rowA) * 32 + kg * 8];
#pragma unroll
        for (int mf = 0; mf < 4; ++mf)
#pragma unroll
            for (int nf = 0; nf < 4; ++nf)
                acc[mf][nf] = __builtin_amdgcn_mfma_f32_16x16x32_bf16(
                    af[mf], bfr[nf], acc[mf][nf], 0, 0, 0);
    }

    float bb[4];
#pragma unroll
    for (int nf = 0; nf < 4; ++nf) bb[nf] = bias[n0 + wn * 64 + nf * 16 + rowA];
#pragma unroll
    for (int mf = 0; mf < 4; ++mf)
#pragma unroll
        for (int nf = 0; nf < 4; ++nf)
#pragma unroll
            for (int r = 0; r < 4; ++r) {
                size_t row = m0 + wm * 64 + mf * 16 + kg * 4 + r;
                size_t col = n0 + wn * 64 + nf * 16 + rowA;
                C[row * N + col] = acc[mf][nf][r] + bb[nf];
            }
}

// ---------------- V transpose: [B,T,H,D] bf16 -> [B,H,D,T] bf16 ----------------
__global__ __launch_bounds__(256) void transpose_v(const u16* __restrict__ v,
                                                   u16* __restrict__ vt) {
    __shared__ u16 tile[64][72];
    const int tid = threadIdx.x;
    const int t0 = blockIdx.x * 64, bh = blockIdx.y;
    const u16* src = v + ((size_t)((bh >> 4) * Tlen + t0)) * Cdim + (bh & 15) * Dh;
#pragma unroll
    for (int i = 0; i < 2; ++i) {
        int ch = tid + i * 256, t = ch >> 3, c = (ch & 7) * 8;
        *(s16x8*)&tile[t][c] = *(const s16x8*)(src + (size_t)t * Cdim + c);
    }
    __syncthreads();
    u16* dst = vt + ((size_t)bh * Dh) * Tlen + t0;
#pragma unroll
    for (int i = 0; i < 2; ++i) {
        int ch = tid + i * 256, d = ch >> 3, tt = (ch & 7) * 8;
        s16x8 o;
#pragma unroll
        for (int j = 0; j < 8; ++j) o[j] = (short)tile[tt + j][d];
        *(s16x8*)(dst + (size_t)d * Tlen + tt) = o;
    }
}

// ---------------- MFMA flash attention (causal), bf16 ----------------
// q pre-scaled by QSCALE. Block = 128 q rows; 4 waves, wave owns 32 rows.
// KV tiles of 64, double-buffered, one barrier per iter. y aliases q (safe:
// each block writes only its own q rows/head cols). qt reversed for balance.
__global__ __launch_bounds__(256, 3) void attn_mfma(const u16* __restrict__ q,
                                                    const u16* __restrict__ k,
                                                    const u16* __restrict__ vt,
                                                    u16* y) {
    const int qt = gridDim.x - 1 - (int)blockIdx.x;   // long blocks first
    const int h = blockIdx.y, b = blockIdx.z;
    const int tid = threadIdx.x, lane = tid & 63, w = tid >> 6;
    __shared__ u16 Ks[2][64 * 64];
    __shared__ u16 Vs[2][64 * 64];
    __shared__ u16 Ps[4][32 * 64];    // per-wave; doubles as Q staging
    const int q0 = qt * 128;
    const int rowA = lane & 15, kg = lane >> 4;
    const int srow8 = lane >> 3, scol8 = lane & 7;

    // stage this wave's 32 Q rows into Ps[w] (swizzled), plus K/V tile 0
    const u16* qbase = q + ((size_t)(b * Tlen + q0 + w * 32)) * Cdim + h * Dh;
#pragma unroll
    for (int i = 0; i < 4; ++i) {
        int row = i * 8 + srow8;
        gload_lds16(qbase + (size_t)row * Cdim + ((scol8 ^ (row & 7)) << 3),
                    Ps[w] + i * 512);
    }
    const u16* kbase = k + ((size_t)(b * Tlen)) * Cdim + h * Dh;
    const u16* vbase = vt + ((size_t)(b * Hn + h)) * (size_t)(Dh * Tlen);
#pragma unroll
    for (int i = 0; i < 2; ++i) {
        int r0 = w * 16 + i * 8, row = r0 + srow8;
        gload_lds16(kbase + (size_t)row * Cdim + ((scol8 ^ (row & 7)) << 3), Ks[0] + r0 * 64);
        gload_lds16(vbase + (size_t)row * Tlen + ((scol8 ^ (row & 7)) << 3), Vs[0] + r0 * 64);
    }
    asm volatile("s_waitcnt vmcnt(0)" ::: "memory");
    __syncthreads();

    // Q fragments -> registers (loop-invariant)
    s16x8 qf[2][2];
#pragma unroll
    for (int mf = 0; mf < 2; ++mf)
#pragma unroll
        for (int ks = 0; ks < 2; ++ks) {
            int qrow = mf * 16 + rowA;
            qf[mf][ks] = *(const s16x8*)&Ps[w][qrow * 64 + ((ks * 32 + kg * 8) ^ ((qrow & 7) << 3))];
        }

    f32x4 acc[2][4] = {};
    float m_i[2][4], l_i[2][4];
#pragma unroll
    for (int mf = 0; mf < 2; ++mf)
#pragma unroll
        for (int r = 0; r < 4; ++r) { m_i[mf][r] = -INFINITY; l_i[mf][r] = 0.f; }

    const int njt = 2 * qt + 2;
    for (int jt = 0; jt < njt; ++jt) {
        const int cur = jt & 1;
        if (jt + 1 < njt) {                       // async prefetch next K/V tile
            const u16* kb2 = kbase + (size_t)(jt + 1) * 64 * Cdim;
            const u16* vb2 = vbase + (jt + 1) * 64;
#pragma unroll
            for (int i = 0; i < 2; ++i) {
                int r0 = w * 16 + i * 8, row = r0 + srow8;
                gload_lds16(kb2 + (size_t)row * Cdim + ((scol8 ^ (row & 7)) << 3), Ks[cur ^ 1] + r0 * 64);
                gload_lds16(vb2 + (size_t)row * Tlen + ((scol8 ^ (row & 7)) << 3), Vs[cur ^ 1] + r0 * 64);
            }
        }
        // S = Q K^T (2 M-frags x 64 keys), K-frag shared across M
        f32x4 sf[2][4] = {};
        __builtin_amdgcn_s_setprio(1);
#pragma unroll
        for (int ks = 0; ks < 2; ++ks)
#pragma unroll
            for (int f = 0; f < 4; ++f) {
                int krow = f * 16 + rowA;
                s16x8 kf = *(const s16x8*)&Ks[cur][krow * 64 + ((ks * 32 + kg * 8) ^ ((krow & 7) << 3))];
#pragma unroll
                for (int mf = 0; mf < 2; ++mf)
                    sf[mf][f] = __builtin_amdgcn_mfma_f32_16x16x32_bf16(qf[mf][ks], kf, sf[mf][f], 0, 0, 0);
            }
        __builtin_amdgcn_s_setprio(0);

        if (jt >= 2 * qt) {                       // diagonal tiles: causal mask
#pragma unroll
            for (int mf = 0; mf < 2; ++mf)
#pragma unroll
                for (int f = 0; f < 4; ++f)
#pragma unroll
                    for (int r = 0; r < 4; ++r) {
                        int kglob = jt * 64 + f * 16 + rowA;
                        int qglob = q0 + w * 32 + mf * 16 + kg * 4 + r;
                        if (kglob > qglob) sf[mf][f][r] = -INFINITY;
                    }
        }
        // online softmax: max-reduce per row; l kept per-lane (reduced once at end)
#pragma unroll
        for (int mf = 0; mf < 2; ++mf)
#pragma unroll
            for (int r = 0; r < 4; ++r) {
                float rm = fmaxf(fmaxf(sf[mf][0][r], sf[mf][1][r]),
                                 fmaxf(sf[mf][2][r], sf[mf][3][r]));
#pragma unroll
                for (int off = 1; off < 16; off <<= 1) rm = fmaxf(rm, __shfl_xor(rm, off));
                float mo = m_i[mf][r];
                float nm = fmaxf(mo, rm);
                float sc = exp2f(mo - nm);
                float p0 = exp2f(sf[mf][0][r] - nm), p1 = exp2f(sf[mf][1][r] - nm);
                float p2 = exp2f(sf[mf][2][r] - nm), p3 = exp2f(sf[mf][3][r] - nm);
                m_i[mf][r] = nm;
                l_i[mf][r] = l_i[mf][r] * sc + (p0 + p1) + (p2 + p3);
#pragma unroll
                for (int db = 0; db < 4; ++db) acc[mf][db][r] *= sc;
                int prow = mf * 16 + kg * 4 + r;
                int pb = prow * 64, sw = (prow & 7) << 3;
                Ps[w][pb + ((0 * 16 + rowA) ^ sw)] = cvt1(p0);
                Ps[w][pb + ((1 * 16 + rowA) ^ sw)] = cvt1(p1);
                Ps[w][pb + ((2 * 16 + rowA) ^ sw)] = cvt1(p2);
                Ps[w][pb + ((3 * 16 + rowA) ^ sw)] = cvt1(p3);
            }
        // O += P @ V
        __builtin_amdgcn_s_setprio(1);
#pragma unroll
        for (int ks = 0; ks < 2; ++ks) {
            s16x8 pa[2];
#pragma unroll
            for (int mf = 0; mf < 2; ++mf) {
                int prow = mf * 16 + rowA;
                pa[mf] = *(const s16x8*)&Ps[w][prow * 64 + ((ks * 32 + kg * 8) ^ ((prow & 7) << 3))];
            }
#pragma unroll
            for (int db = 0; db < 4; ++db) {
                int vrow = db * 16 + rowA;
                s16x8 vb = *(const s16x8*)&Vs[cur][vrow * 64 + ((ks * 32 + kg * 8) ^ ((vrow & 7) << 3))];
#pragma unroll
                for (int mf = 0; mf < 2; ++mf)
                    acc[mf][db] = __builtin_amdgcn_mfma_f32_16x16x32_bf16(pa[mf], vb, acc[mf][db], 0, 0, 0);
            }
        }
        __builtin_amdgcn_s_setprio(0);

        asm volatile("s_waitcnt vmcnt(0)" ::: "memory");   // prefetch landed
        __syncthreads();                                    // all waves done reading cur
    }

    u16* ybase = y + ((size_t)(b * Tlen + q0 + w * 32)) * Cdim + h * Dh;
#pragma unroll
    for (int mf = 0; mf < 2; ++mf)
#pragma unroll
        for (int r = 0; r < 4; ++r) {
            float l = l_i[mf][r];
#pragma unroll
            for (int off = 1; off < 16; off <<= 1) l += __shfl_xor(l, off);
            float inv = 1.f / l;
#pragma unroll
            for (int db = 0; db < 4; ++db)
                ybase[(size_t)(mf * 16 + kg * 4 + r) * Cdim + db * 16 + rowA] =
                    cvt1(acc[mf][db][r] * inv);
        }
}

extern "C" void kernel_launch(void* const* d_in, const int* in_sizes, int n_in,
                              void* d_out, int out_size, void* d_ws, size_t ws_size,
                              hipStream_t stream) {
    const float* x  = (const float*)d_in[0];
    const float* Wq = (const float*)d_in[1];
    const float* bq = (const float*)d_in[2];
    const float* Wk = (const float*)d_in[3];
    const float* bk = (const float*)d_in[4];
    const float* Wv = (const float*)d_in[5];
    const float* bv = (const float*)d_in[6];
    const float* Wp = (const float*)d_in[7];
    const float* bp = (const float*)d_in[8];
    float* out = (float*)d_out;

    const size_t plane = (size_t)Mtot * Cdim;   // 8M elems
    const size_t wsz   = (size_t)Cdim * Cdim;   // 1M elems
    u16* xb    = (u16*)d_ws;
    u16* wqkvb = xb + plane;                    // 3M (Wq|Wk|Wv)
    u16* wpb   = wqkvb + 3 * wsz;
    u16* qb    = wpb + wsz;                     // q/k/v contiguous planes
    u16* kb    = qb + plane;
    u16* vb    = kb + plane;
    u16* vtb   = vb + plane;                    // total 88 MiB

    cvt_bf16<<<plane / 2048, 256, 0, stream>>>(x, xb);
    cvt_bf16<<<wsz / 2048, 256, 0, stream>>>(Wq, wqkvb);
    cvt_bf16<<<wsz / 2048, 256, 0, stream>>>(Wk, wqkvb + wsz);
    cvt_bf16<<<wsz / 2048, 256, 0, stream>>>(Wv, wqkvb + 2 * wsz);
    cvt_bf16<<<wsz / 2048, 256, 0, stream>>>(Wp, wpb);

    gemm_qkv<<<dim3(Mtot / 128, 3 * Cdim / 128), 256, 0, stream>>>(
        xb, wqkvb, bq, bk, bv, qb);

    transpose_v<<<dim3(Tlen / 64, Bn * Hn), 256, 0, stream>>>(vb, vtb);

    attn_mfma<<<dim3(Tlen / 128, Hn, Bn), 256, 0, stream>>>(qb, kb, vtb, qb);

    gemm_proj<<<dim3(Mtot / 128, Cdim / 128), 256, 0, stream>>>(qb, wpb, bp, out);
}

// Round 4
// 242.648 us; speedup vs baseline: 13.3250x; 1.4378x over previous
//
#include <hip/hip_runtime.h>
#include <hip/hip_bf16.h>
#include <math.h>

static constexpr int Bn = 4, Tlen = 2048, Cdim = 1024, Hn = 16, Dh = 64;
static constexpr int Mtot = Bn * Tlen;

typedef __attribute__((ext_vector_type(8)))  short    s16x8;
typedef __attribute__((ext_vector_type(4)))  float    f32x4;
typedef __attribute__((ext_vector_type(16))) float    f32x16;
typedef __attribute__((ext_vector_type(2)))  unsigned u32x2;
typedef unsigned short u16;

// scale folded into Q: (1/sqrt(64)) * log2(e)
#define QSCALE 0.18033688011112042f

__device__ __forceinline__ u16 f2bf(float f) {
    union { float f; unsigned u; } x; x.f = f;
    unsigned r = x.u + 0x7FFFu + ((x.u >> 16) & 1u);   // RNE
    return (u16)(r >> 16);
}
__device__ __forceinline__ unsigned cvtpk(float lo, float hi) {
    unsigned r;
    asm("v_cvt_pk_bf16_f32 %0, %1, %2" : "=v"(r) : "v"(lo), "v"(hi));
    return r;
}
__device__ __forceinline__ void gload_lds16(const void* g, void* l) {
    __builtin_amdgcn_global_load_lds(
        (const __attribute__((address_space(1))) void*)g,
        (__attribute__((address_space(3))) void*)l, 16, 0, 0);
}

// ---------------- fp32 -> bf16 convert (vectorized) ----------------
__global__ __launch_bounds__(256) void cvt_bf16(const float* __restrict__ in,
                                                u16* __restrict__ out) {
    size_t i = (size_t)(blockIdx.x * 256 + threadIdx.x) * 8;
    float4 a = *(const float4*)(in + i);
    float4 b = *(const float4*)(in + i + 4);
    s16x8 o;
    o[0] = (short)f2bf(a.x); o[1] = (short)f2bf(a.y);
    o[2] = (short)f2bf(a.z); o[3] = (short)f2bf(a.w);
    o[4] = (short)f2bf(b.x); o[5] = (short)f2bf(b.y);
    o[6] = (short)f2bf(b.z); o[7] = (short)f2bf(b.w);
    *(s16x8*)(out + i) = o;
}

// ---------------- fused QKV GEMM: A[8192,1024] x Wqkv[3072,1024]^T ----------------
__global__ __launch_bounds__(256) void gemm_qkv(const u16* __restrict__ A,
                                                const u16* __restrict__ B,
                                                const float* __restrict__ bq,
                                                const float* __restrict__ bk,
                                                const float* __restrict__ bv,
                                                u16* __restrict__ outbase) {
    constexpr int K = Cdim, N = Cdim;
    __shared__ u16 As[128 * 32];
    __shared__ u16 Bs[128 * 32];
    const int tid = threadIdx.x, lane = tid & 63, w = tid >> 6;
    const int m0 = blockIdx.x * 128, n0g = blockIdx.y * 128;
    const int which = n0g >> 10, n0 = n0g & 1023;
    const float* bias = which == 0 ? bq : (which == 1 ? bk : bv);
    const float osc = which == 0 ? QSCALE : 1.0f;
    u16* C = outbase + (size_t)which * ((size_t)Mtot * Cdim);
    const int wm = w >> 1, wn = w & 1;
    const int rowA = lane & 15, kg = lane >> 4;
    const int srow = lane >> 2, sc4 = (lane & 3) * 8;

    f32x4 acc[4][4] = {};
    const u16* Abase = A + (size_t)m0 * K;
    const u16* Bbase = B + (size_t)n0g * K;

    for (int k0 = 0; k0 < K; k0 += 32) {
        __syncthreads();
#pragma unroll
        for (int i = 0; i < 2; ++i) {
            int r0 = w * 32 + i * 16;
            gload_lds16(Abase + (size_t)(r0 + srow) * K + k0 + sc4, As + r0 * 32);
            gload_lds16(Bbase + (size_t)(r0 + srow) * K + k0 + sc4, Bs + r0 * 32);
        }
        asm volatile("s_waitcnt vmcnt(0)" ::: "memory");
        __syncthreads();

        s16x8 af[4], bfr[4];
#pragma unroll
        for (int mf = 0; mf < 4; ++mf)
            af[mf] = *(const s16x8*)&As[(wm * 64 + mf * 16 + rowA) * 32 + kg * 8];
#pragma unroll
        for (int nf = 0; nf < 4; ++nf)
            bfr[nf] = *(const s16x8*)&Bs[(wn * 64 + nf * 16 + rowA) * 32 + kg * 8];
#pragma unroll
        for (int mf = 0; mf < 4; ++mf)
#pragma unroll
            for (int nf = 0; nf < 4; ++nf)
                acc[mf][nf] = __builtin_amdgcn_mfma_f32_16x16x32_bf16(
                    af[mf], bfr[nf], acc[mf][nf], 0, 0, 0);
    }

    float bb[4];
#pragma unroll
    for (int nf = 0; nf < 4; ++nf) bb[nf] = bias[n0 + wn * 64 + nf * 16 + rowA];
#pragma unroll
    for (int mf = 0; mf < 4; ++mf)
#pragma unroll
        for (int nf = 0; nf < 4; ++nf)
#pragma unroll
            for (int r = 0; r < 4; ++r) {
                float val = (acc[mf][nf][r] + bb[nf]) * osc;
                size_t row = m0 + wm * 64 + mf * 16 + kg * 4 + r;
                size_t col = n0 + wn * 64 + nf * 16 + rowA;
                C[row * N + col] = f2bf(val);
            }
}

// ---------------- out-proj GEMM: bf16 A,B -> fp32 out ----------------
__global__ __launch_bounds__(256) void gemm_proj(const u16* __restrict__ A,
                                                 const u16* __restrict__ B,
                                                 const float* __restrict__ bias,
                                                 float* __restrict__ C) {
    constexpr int K = Cdim, N = Cdim;
    __shared__ u16 As[128 * 32];
    __shared__ u16 Bs[128 * 32];
    const int tid = threadIdx.x, lane = tid & 63, w = tid >> 6;
    const int m0 = blockIdx.x * 128, n0 = blockIdx.y * 128;
    const int wm = w >> 1, wn = w & 1;
    const int rowA = lane & 15, kg = lane >> 4;
    const int srow = lane >> 2, sc4 = (lane & 3) * 8;

    f32x4 acc[4][4] = {};
    const u16* Abase = A + (size_t)m0 * K;
    const u16* Bbase = B + (size_t)n0 * K;

    for (int k0 = 0; k0 < K; k0 += 32) {
        __syncthreads();
#pragma unroll
        for (int i = 0; i < 2; ++i) {
            int r0 = w * 32 + i * 16;
            gload_lds16(Abase + (size_t)(r0 + srow) * K + k0 + sc4, As + r0 * 32);
            gload_lds16(Bbase + (size_t)(r0 + srow) * K + k0 + sc4, Bs + r0 * 32);
        }
        asm volatile("s_waitcnt vmcnt(0)" ::: "memory");
        __syncthreads();

        s16x8 af[4], bfr[4];
#pragma unroll
        for (int mf = 0; mf < 4; ++mf)
            af[mf] = *(const s16x8*)&As[(wm * 64 + mf * 16 + rowA) * 32 + kg * 8];
#pragma unroll
        for (int nf = 0; nf < 4; ++nf)
            bfr[nf] = *(const s16x8*)&Bs[(wn * 64 + nf * 16 + rowA) * 32 + kg * 8];
#pragma unroll
        for (int mf = 0; mf < 4; ++mf)
#pragma unroll
            for (int nf = 0; nf < 4; ++nf)
                acc[mf][nf] = __builtin_amdgcn_mfma_f32_16x16x32_bf16(
                    af[mf], bfr[nf], acc[mf][nf], 0, 0, 0);
    }

    float bb[4];
#pragma unroll
    for (int nf = 0; nf < 4; ++nf) bb[nf] = bias[n0 + wn * 64 + nf * 16 + rowA];
#pragma unroll
    for (int mf = 0; mf < 4; ++mf)
#pragma unroll
        for (int nf = 0; nf < 4; ++nf)
#pragma unroll
            for (int r = 0; r < 4; ++r) {
                size_t row = m0 + wm * 64 + mf * 16 + kg * 4 + r;
                size_t col = n0 + wn * 64 + nf * 16 + rowA;
                C[row * N + col] = acc[mf][nf][r] + bb[nf];
            }
}

// ---------------- V transpose: [B,T,H,D] bf16 -> [B,H,D,T] bf16 ----------------
__global__ __launch_bounds__(256) void transpose_v(const u16* __restrict__ v,
                                                   u16* __restrict__ vt) {
    __shared__ u16 tile[64][72];
    const int tid = threadIdx.x;
    const int t0 = blockIdx.x * 64, bh = blockIdx.y;
    const u16* src = v + ((size_t)((bh >> 4) * Tlen + t0)) * Cdim + (bh & 15) * Dh;
#pragma unroll
    for (int i = 0; i < 2; ++i) {
        int ch = tid + i * 256, t = ch >> 3, c = (ch & 7) * 8;
        *(s16x8*)&tile[t][c] = *(const s16x8*)(src + (size_t)t * Cdim + c);
    }
    __syncthreads();
    u16* dst = vt + ((size_t)bh * Dh) * Tlen + t0;
#pragma unroll
    for (int i = 0; i < 2; ++i) {
        int ch = tid + i * 256, d = ch >> 3, tt = (ch & 7) * 8;
        s16x8 o;
#pragma unroll
        for (int j = 0; j < 8; ++j) o[j] = (short)tile[tt + j][d];
        *(s16x8*)(dst + (size_t)d * Tlen + tt) = o;
    }
}

// ---------------- MFMA flash attention, 32x32 swapped-operand ----------------
// q pre-scaled by QSCALE*log2e fold. Block = 256 q rows, 8 waves x 32 rows.
// S^T = mfma(Kfrag, Qfrag): lane owns q=lane&31; softmax in-register.
// O^T = mfma(Vtfrag, Pfrag): col=q=lane&31 -> per-lane rescale/normalize.
// y aliases q (block writes only its own rows/head cols; Q consumed upfront).
__global__ __launch_bounds__(512, 2) void attn_mfma(const u16* __restrict__ q,
                                                    const u16* __restrict__ k,
                                                    const u16* __restrict__ vt,
                                                    u16* y) {
    const int qt = gridDim.x - 1 - (int)blockIdx.x;   // LPT: long blocks first
    const int h = blockIdx.y, b = blockIdx.z;
    const int tid = threadIdx.x, lane = tid & 63, w = tid >> 6;
    const int qlane = lane & 31, hi = lane >> 5;
    __shared__ u16 Ks[2][64 * 64];
    __shared__ u16 Vs[2][64 * 64];

    const int q0 = qt * 256;
    const int qrow_g = q0 + w * 32 + qlane;

    // Q fragments to registers: step s covers d = 16s + 8*hi + [0,8)
    const u16* qrow = q + ((size_t)(b * Tlen) + qrow_g) * Cdim + h * Dh;
    s16x8 qf[4];
#pragma unroll
    for (int s = 0; s < 4; ++s)
        qf[s] = *(const s16x8*)(qrow + s * 16 + hi * 8);

    // staging: lane stages one 16B chunk of K and V^T per tile
    const u16* kbase = k + ((size_t)(b * Tlen)) * Cdim + h * Dh;
    const u16* vbase = vt + ((size_t)(b * Hn + h)) * (size_t)(Dh * Tlen);
    const int srow = w * 8 + (lane >> 3);
    const int scol = ((lane & 7) ^ (srow & 7)) * 8;   // pre-swizzled source col

    gload_lds16(kbase + (size_t)srow * Cdim + scol, &Ks[0][w * 512]);
    gload_lds16(vbase + (size_t)srow * Tlen + scol, &Vs[0][w * 512]);
    asm volatile("s_waitcnt vmcnt(0)" ::: "memory");
    __syncthreads();

    f32x16 o0, o1;
#pragma unroll
    for (int r = 0; r < 16; ++r) { o0[r] = 0.f; o1[r] = 0.f; }
    float m_i = -INFINITY, l_i = 0.f;

    const int njt = 4 * qt + 4;
    const int jtmax = (q0 + w * 32 + 31) >> 6;   // last tile this wave needs
    const int swz = (qlane & 7);

    for (int jt = 0; jt < njt; ++jt) {
        const int cur = jt & 1;
        if (jt + 1 < njt) {   // async prefetch next K/V tile into other buffer
            gload_lds16(kbase + (size_t)((jt + 1) * 64 + srow) * Cdim + scol,
                        &Ks[cur ^ 1][w * 512]);
            gload_lds16(vbase + (size_t)srow * Tlen + (jt + 1) * 64 + scol,
                        &Vs[cur ^ 1][w * 512]);
        }
        if (jt <= jtmax) {
            // ---- S^T = K Q^T : two 32-kv subtiles
            f32x16 sA, sB;
#pragma unroll
            for (int r = 0; r < 16; ++r) { sA[r] = 0.f; sB[r] = 0.f; }
            __builtin_amdgcn_s_setprio(1);
#pragma unroll
            for (int s = 0; s < 4; ++s) {
                const int g8 = ((2 * s + hi) ^ swz) * 8;
                s16x8 k0 = *(const s16x8*)&Ks[cur][qlane * 64 + g8];
                s16x8 k1 = *(const s16x8*)&Ks[cur][(qlane + 32) * 64 + g8];
                sA = __builtin_amdgcn_mfma_f32_32x32x16_bf16(k0, qf[s], sA, 0, 0, 0);
                sB = __builtin_amdgcn_mfma_f32_32x32x16_bf16(k1, qf[s], sB, 0, 0, 0);
            }
            __builtin_amdgcn_s_setprio(0);

            // ---- causal mask (only near-diagonal tiles)
            if (jt * 64 + 63 > q0 + w * 32) {
#pragma unroll
                for (int r = 0; r < 16; ++r) {
                    int kv = jt * 64 + (r & 3) + 8 * (r >> 2) + 4 * hi;
                    if (kv > qrow_g)      sA[r] = -INFINITY;
                    if (kv + 32 > qrow_g) sB[r] = -INFINITY;
                }
            }
            // ---- online softmax, in-register (q = lane&31)
            float pm = -INFINITY;
#pragma unroll
            for (int r = 0; r < 16; ++r) pm = fmaxf(pm, fmaxf(sA[r], sB[r]));
            pm = fmaxf(pm, __shfl_xor(pm, 32));
            float nm = fmaxf(m_i, pm);
            float sc = exp2f(m_i - nm);
            m_i = nm;
            float ps = 0.f;
#pragma unroll
            for (int r = 0; r < 16; ++r) {
                sA[r] = exp2f(sA[r] - nm); ps += sA[r];
                sB[r] = exp2f(sB[r] - nm); ps += sB[r];
            }
            ps += __shfl_xor(ps, 32);
            l_i = l_i * sc + ps;
#pragma unroll
            for (int r = 0; r < 16; ++r) { o0[r] *= sc; o1[r] *= sc; }

            // ---- pack P (C/D layout) -> 4 MFMA B-frags via cvt_pk + shfl
            s16x8 pf[4];
            auto packsub = [&](const f32x16& sv, s16x8* out) {
#pragma unroll
                for (int t = 0; t < 2; ++t) {
                    unsigned X = cvtpk(sv[8 * t + 0], sv[8 * t + 1]);
                    unsigned Z = cvtpk(sv[8 * t + 2], sv[8 * t + 3]);
                    unsigned Y = cvtpk(sv[8 * t + 4], sv[8 * t + 5]);
                    unsigned W = cvtpk(sv[8 * t + 6], sv[8 * t + 7]);
                    unsigned U0 = hi ? Y : X, V0 = hi ? X : Y;
                    unsigned U1 = hi ? W : Z, V1 = hi ? Z : W;
                    unsigned S0 = (unsigned)__shfl_xor((int)V0, 32);
                    unsigned S1 = (unsigned)__shfl_xor((int)V1, 32);
                    union { unsigned u[4]; s16x8 v; } fr;
                    fr.u[0] = hi ? S0 : U0;
                    fr.u[1] = hi ? S1 : U1;
                    fr.u[2] = hi ? U0 : S0;
                    fr.u[3] = hi ? U1 : S1;
                    out[t] = fr.v;
                }
            };
            packsub(sA, pf);
            packsub(sB, pf + 2);

            // ---- O^T += V^T P^T : frag t covers kv = 16t + 8hi + [0,8)
            __builtin_amdgcn_s_setprio(1);
#pragma unroll
            for (int t = 0; t < 4; ++t) {
                const int g8 = ((2 * t + hi) ^ swz) * 8;
                s16x8 v0 = *(const s16x8*)&Vs[cur][qlane * 64 + g8];
                s16x8 v1 = *(const s16x8*)&Vs[cur][(qlane + 32) * 64 + g8];
                o0 = __builtin_amdgcn_mfma_f32_32x32x16_bf16(v0, pf[t], o0, 0, 0, 0);
                o1 = __builtin_amdgcn_mfma_f32_32x32x16_bf16(v1, pf[t], o1, 0, 0, 0);
            }
            __builtin_amdgcn_s_setprio(0);
        }
        asm volatile("s_waitcnt vmcnt(0)" ::: "memory");   // prefetch landed
        __syncthreads();                                    // all waves done with cur
    }

    // ---- normalize + write: lane owns q-row qrow_g; d = (r&3)+8*(r>>2)+4hi(+32)
    float inv = 1.f / l_i;
    u16* yrow = y + ((size_t)(b * Tlen) + qrow_g) * Cdim + h * Dh;
#pragma unroll
    for (int g2 = 0; g2 < 4; ++g2) {
        u32x2 st;
        st[0] = cvtpk(o0[4 * g2 + 0] * inv, o0[4 * g2 + 1] * inv);
        st[1] = cvtpk(o0[4 * g2 + 2] * inv, o0[4 * g2 + 3] * inv);
        *(u32x2*)(yrow + 8 * g2 + 4 * hi) = st;
        st[0] = cvtpk(o1[4 * g2 + 0] * inv, o1[4 * g2 + 1] * inv);
        st[1] = cvtpk(o1[4 * g2 + 2] * inv, o1[4 * g2 + 3] * inv);
        *(u32x2*)(yrow + 32 + 8 * g2 + 4 * hi) = st;
    }
}

extern "C" void kernel_launch(void* const* d_in, const int* in_sizes, int n_in,
                              void* d_out, int out_size, void* d_ws, size_t ws_size,
                              hipStream_t stream) {
    const float* x  = (const float*)d_in[0];
    const float* Wq = (const float*)d_in[1];
    const float* bq = (const float*)d_in[2];
    const float* Wk = (const float*)d_in[3];
    const float* bk = (const float*)d_in[4];
    const float* Wv = (const float*)d_in[5];
    const float* bv = (const float*)d_in[6];
    const float* Wp = (const float*)d_in[7];
    const float* bp = (const float*)d_in[8];
    float* out = (float*)d_out;

    const size_t plane = (size_t)Mtot * Cdim;   // 8M elems
    const size_t wsz   = (size_t)Cdim * Cdim;   // 1M elems
    u16* xb    = (u16*)d_ws;
    u16* wqkvb = xb + plane;                    // Wq|Wk|Wv
    u16* wpb   = wqkvb + 3 * wsz;
    u16* qb    = wpb + wsz;                     // q/k/v contiguous planes
    u16* kb    = qb + plane;
    u16* vb    = kb + plane;
    u16* vtb   = vb + plane;

    cvt_bf16<<<plane / 2048, 256, 0, stream>>>(x, xb);
    cvt_bf16<<<wsz / 2048, 256, 0, stream>>>(Wq, wqkvb);
    cvt_bf16<<<wsz / 2048, 256, 0, stream>>>(Wk, wqkvb + wsz);
    cvt_bf16<<<wsz / 2048, 256, 0, stream>>>(Wv, wqkvb + 2 * wsz);
    cvt_bf16<<<wsz / 2048, 256, 0, stream>>>(Wp, wpb);

    gemm_qkv<<<dim3(Mtot / 128, 3 * Cdim / 128), 256, 0, stream>>>(
        xb, wqkvb, bq, bk, bv, qb);

    transpose_v<<<dim3(Tlen / 64, Bn * Hn), 256, 0, stream>>>(vb, vtb);

    attn_mfma<<<dim3(Tlen / 256, Hn, Bn), 512, 0, stream>>>(qb, kb, vtb, qb);

    gemm_proj<<<dim3(Mtot / 128, Cdim / 128), 256, 0, stream>>>(qb, wpb, bp, out);
}

// Round 5
// 213.873 us; speedup vs baseline: 15.1177x; 1.1345x over previous
//
#include <hip/hip_runtime.h>
#include <hip/hip_bf16.h>
#include <math.h>

static constexpr int Bn = 4, Tlen = 2048, Cdim = 1024, Hn = 16, Dh = 64;
static constexpr int Mtot = Bn * Tlen;

typedef __attribute__((ext_vector_type(8)))  short    s16x8;
typedef __attribute__((ext_vector_type(4)))  float    f32x4;
typedef __attribute__((ext_vector_type(16))) float    f32x16;
typedef __attribute__((ext_vector_type(2)))  unsigned u32x2;
typedef unsigned short u16;

// scale folded into Q: (1/sqrt(64)) * log2(e)
#define QSCALE 0.18033688011112042f

__device__ __forceinline__ u16 f2bf(float f) {
    union { float f; unsigned u; } x; x.f = f;
    unsigned r = x.u + 0x7FFFu + ((x.u >> 16) & 1u);   // RNE
    return (u16)(r >> 16);
}
__device__ __forceinline__ unsigned cvtpk(float lo, float hi) {
    unsigned r;
    asm("v_cvt_pk_bf16_f32 %0, %1, %2" : "=v"(r) : "v"(lo), "v"(hi));
    return r;
}
__device__ __forceinline__ void gload_lds16(const void* g, void* l) {
    __builtin_amdgcn_global_load_lds(
        (const __attribute__((address_space(1))) void*)g,
        (__attribute__((address_space(3))) void*)l, 16, 0, 0);
}

// ---------------- fp32 -> bf16 convert (vectorized) ----------------
__global__ __launch_bounds__(256) void cvt_bf16(const float* __restrict__ in,
                                                u16* __restrict__ out) {
    size_t i = (size_t)(blockIdx.x * 256 + threadIdx.x) * 8;
    float4 a = *(const float4*)(in + i);
    float4 b = *(const float4*)(in + i + 4);
    s16x8 o;
    o[0] = (short)f2bf(a.x); o[1] = (short)f2bf(a.y);
    o[2] = (short)f2bf(a.z); o[3] = (short)f2bf(a.w);
    o[4] = (short)f2bf(b.x); o[5] = (short)f2bf(b.y);
    o[6] = (short)f2bf(b.z); o[7] = (short)f2bf(b.w);
    *(s16x8*)(out + i) = o;
}

// ---------------- fused QKV GEMM: A[8192,1024] x Wqkv[3072,1024]^T ----------------
// q plane scaled by QSCALE; v plane written TRANSPOSED to vt [B, H*D, T].
__global__ __launch_bounds__(256) void gemm_qkv(const u16* __restrict__ A,
                                                const u16* __restrict__ B,
                                                const float* __restrict__ bq,
                                                const float* __restrict__ bk,
                                                const float* __restrict__ bv,
                                                u16* __restrict__ qkbase,
                                                u16* __restrict__ vt) {
    constexpr int K = Cdim, N = Cdim;
    __shared__ u16 As[128 * 32];
    __shared__ u16 Bs[128 * 32];
    // bijective XCD swizzle: 1536 blocks = 8 * 192
    const int f = blockIdx.y * gridDim.x + blockIdx.x;
    const int f2 = (f & 7) * ((int)(gridDim.x * gridDim.y) >> 3) + (f >> 3);
    const int bxs = f2 & 63, bys = f2 >> 6;

    const int tid = threadIdx.x, lane = tid & 63, w = tid >> 6;
    const int m0 = bxs * 128, n0g = bys * 128;
    const int which = n0g >> 10, n0 = n0g & 1023;
    const float* bias = which == 0 ? bq : (which == 1 ? bk : bv);
    const float osc = which == 0 ? QSCALE : 1.0f;
    const int wm = w >> 1, wn = w & 1;
    const int rowA = lane & 15, kg = lane >> 4;
    const int srow = lane >> 2, sc4 = (lane & 3) * 8;

    f32x4 acc[4][4] = {};
    const u16* Abase = A + (size_t)m0 * K;
    const u16* Bbase = B + (size_t)n0g * K;

    for (int k0 = 0; k0 < K; k0 += 32) {
        __syncthreads();
#pragma unroll
        for (int i = 0; i < 2; ++i) {
            int r0 = w * 32 + i * 16;
            gload_lds16(Abase + (size_t)(r0 + srow) * K + k0 + sc4, As + r0 * 32);
            gload_lds16(Bbase + (size_t)(r0 + srow) * K + k0 + sc4, Bs + r0 * 32);
        }
        asm volatile("s_waitcnt vmcnt(0)" ::: "memory");
        __syncthreads();

        s16x8 af[4], bfr[4];
#pragma unroll
        for (int mf = 0; mf < 4; ++mf)
            af[mf] = *(const s16x8*)&As[(wm * 64 + mf * 16 + rowA) * 32 + kg * 8];
#pragma unroll
        for (int nf = 0; nf < 4; ++nf)
            bfr[nf] = *(const s16x8*)&Bs[(wn * 64 + nf * 16 + rowA) * 32 + kg * 8];
#pragma unroll
        for (int mf = 0; mf < 4; ++mf)
#pragma unroll
            for (int nf = 0; nf < 4; ++nf)
                acc[mf][nf] = __builtin_amdgcn_mfma_f32_16x16x32_bf16(
                    af[mf], bfr[nf], acc[mf][nf], 0, 0, 0);
    }

    float bb[4];
#pragma unroll
    for (int nf = 0; nf < 4; ++nf) bb[nf] = bias[n0 + wn * 64 + nf * 16 + rowA];

    if (which < 2) {
        u16* C = qkbase + (size_t)which * ((size_t)Mtot * Cdim);
#pragma unroll
        for (int mf = 0; mf < 4; ++mf)
#pragma unroll
            for (int nf = 0; nf < 4; ++nf)
#pragma unroll
                for (int r = 0; r < 4; ++r) {
                    float val = (acc[mf][nf][r] + bb[nf]) * osc;
                    size_t row = m0 + wm * 64 + mf * 16 + kg * 4 + r;
                    size_t col = n0 + wn * 64 + nf * 16 + rowA;
                    C[row * N + col] = f2bf(val);
                }
    } else {
        // V plane -> write transposed: vt[b*1024 + (h*64+d)][t], 4 consecutive t per frag
#pragma unroll
        for (int mf = 0; mf < 4; ++mf)
#pragma unroll
            for (int nf = 0; nf < 4; ++nf) {
                int hd = n0 + wn * 64 + nf * 16 + rowA;
                size_t row0 = m0 + wm * 64 + mf * 16 + kg * 4;
                int bi = (int)(row0 >> 11), t0 = (int)(row0 & 2047);
                union { u16 h[4]; u32x2 d; } pk;
#pragma unroll
                for (int r = 0; r < 4; ++r) pk.h[r] = f2bf(acc[mf][nf][r] + bb[nf]);
                *(u32x2*)(vt + ((size_t)bi * 1024 + hd) * Tlen + t0) = pk.d;
            }
    }
}

// ---------------- out-proj GEMM: bf16 A,B -> fp32 out ----------------
__global__ __launch_bounds__(256) void gemm_proj(const u16* __restrict__ A,
                                                 const u16* __restrict__ B,
                                                 const float* __restrict__ bias,
                                                 float* __restrict__ C) {
    constexpr int K = Cdim, N = Cdim;
    __shared__ u16 As[128 * 32];
    __shared__ u16 Bs[128 * 32];
    const int f = blockIdx.y * gridDim.x + blockIdx.x;    // 512 = 8 * 64
    const int f2 = (f & 7) * ((int)(gridDim.x * gridDim.y) >> 3) + (f >> 3);
    const int bxs = f2 & 63, bys = f2 >> 6;

    const int tid = threadIdx.x, lane = tid & 63, w = tid >> 6;
    const int m0 = bxs * 128, n0 = bys * 128;
    const int wm = w >> 1, wn = w & 1;
    const int rowA = lane & 15, kg = lane >> 4;
    const int srow = lane >> 2, sc4 = (lane & 3) * 8;

    f32x4 acc[4][4] = {};
    const u16* Abase = A + (size_t)m0 * K;
    const u16* Bbase = B + (size_t)n0 * K;

    for (int k0 = 0; k0 < K; k0 += 32) {
        __syncthreads();
#pragma unroll
        for (int i = 0; i < 2; ++i) {
            int r0 = w * 32 + i * 16;
            gload_lds16(Abase + (size_t)(r0 + srow) * K + k0 + sc4, As + r0 * 32);
            gload_lds16(Bbase + (size_t)(r0 + srow) * K + k0 + sc4, Bs + r0 * 32);
        }
        asm volatile("s_waitcnt vmcnt(0)" ::: "memory");
        __syncthreads();

        s16x8 af[4], bfr[4];
#pragma unroll
        for (int mf = 0; mf < 4; ++mf)
            af[mf] = *(const s16x8*)&As[(wm * 64 + mf * 16 + rowA) * 32 + kg * 8];
#pragma unroll
        for (int nf = 0; nf < 4; ++nf)
            bfr[nf] = *(const s16x8*)&Bs[(wn * 64 + nf * 16 + rowA) * 32 + kg * 8];
#pragma unroll
        for (int mf = 0; mf < 4; ++mf)
#pragma unroll
            for (int nf = 0; nf < 4; ++nf)
                acc[mf][nf] = __builtin_amdgcn_mfma_f32_16x16x32_bf16(
                    af[mf], bfr[nf], acc[mf][nf], 0, 0, 0);
    }

    float bb[4];
#pragma unroll
    for (int nf = 0; nf < 4; ++nf) bb[nf] = bias[n0 + wn * 64 + nf * 16 + rowA];
#pragma unroll
    for (int mf = 0; mf < 4; ++mf)
#pragma unroll
        for (int nf = 0; nf < 4; ++nf)
#pragma unroll
            for (int r = 0; r < 4; ++r) {
                size_t row = m0 + wm * 64 + mf * 16 + kg * 4 + r;
                size_t col = n0 + wn * 64 + nf * 16 + rowA;
                C[row * N + col] = acc[mf][nf][r] + bb[nf];
            }
}

// ---------------- MFMA flash attention, 32x32 swapped-operand ----------------
// 256 threads = 4 waves, 128 q-rows/block; wave w owns rows q0+w*32+[0,32).
// Flat 1024-block grid, LPT order (long qt first). Counted-vmcnt double buffer
// with raw s_barrier (no vmcnt(0) drain in steady state).
__global__ __launch_bounds__(256, 4) void attn_mfma(const u16* __restrict__ q,
                                                    const u16* __restrict__ k,
                                                    const u16* __restrict__ vt,
                                                    u16* y) {
    const int fid = blockIdx.x;
    const int qt = 15 - (fid >> 6);                 // LPT: qt=15 dispatched first
    const int rem = fid & 63;
    const int h = rem & 15, b = rem >> 4;
    const int tid = threadIdx.x, lane = tid & 63, w = tid >> 6;
    const int qlane = lane & 31, hi = lane >> 5;
    __shared__ u16 Ks[2][64 * 64];
    __shared__ u16 Vs[2][64 * 64];

    const int q0 = qt * 128;
    const int qrow_g = q0 + w * 32 + qlane;

    // Q fragments to registers: step s covers d = 16s + 8*hi + [0,8)
    const u16* qrow = q + ((size_t)(b * Tlen) + qrow_g) * Cdim + h * Dh;
    s16x8 qf[4];
#pragma unroll
    for (int s = 0; s < 4; ++s)
        qf[s] = *(const s16x8*)(qrow + s * 16 + hi * 8);

    const u16* kbase = k + ((size_t)(b * Tlen)) * Cdim + h * Dh;
    const u16* vbase = vt + ((size_t)(b * Hn + h)) * (size_t)(Dh * Tlen);

    // staging: thread stages granules tid and tid+256 of each 512-granule tile
    const int g0row = tid >> 3;
    const int g1row = g0row + 32;
    const int gc0 = (((tid) & 7) ^ (g0row & 7)) * 8;   // pre-swizzled source col
    const int gc1 = (((tid) & 7) ^ (g1row & 7)) * 8;

#define STAGE(JT, BUF)                                                              \
    do {                                                                            \
        const u16* kb2 = kbase + (size_t)((JT) * 64) * Cdim;                        \
        const u16* vb2 = vbase + (JT) * 64;                                         \
        gload_lds16(kb2 + (size_t)g0row * Cdim + gc0, &Ks[BUF][w * 512]);           \
        gload_lds16(kb2 + (size_t)g1row * Cdim + gc1, &Ks[BUF][2048 + w * 512]);    \
        gload_lds16(vb2 + (size_t)g0row * Tlen + gc0, &Vs[BUF][w * 512]);           \
        gload_lds16(vb2 + (size_t)g1row * Tlen + gc1, &Vs[BUF][2048 + w * 512]);    \
    } while (0)

    STAGE(0, 0);

    f32x16 o0, o1;
#pragma unroll
    for (int r = 0; r < 16; ++r) { o0[r] = 0.f; o1[r] = 0.f; }
    float m_i = -INFINITY, l_i = 0.f;

    const int njt = 2 * qt + 2;
    const int jtmax = 2 * qt + (w >> 1);          // last tile this wave needs
    const int swz = (qlane & 7);

    for (int jt = 0; jt < njt; ++jt) {
        const int cur = jt & 1;
        if (jt + 1 < njt) {
            STAGE(jt + 1, cur ^ 1);
            asm volatile("s_waitcnt vmcnt(4)" ::: "memory");   // cur landed, next in flight
        } else {
            asm volatile("s_waitcnt vmcnt(0)" ::: "memory");
        }
        __builtin_amdgcn_s_barrier();              // all waves' cur data visible

        if (jt <= jtmax) {
            const u16* kc = &Ks[cur][0];
            const u16* vc = &Vs[cur][0];
            // ---- S^T = K Q^T : two 32-kv subtiles
            f32x16 sA, sB;
#pragma unroll
            for (int r = 0; r < 16; ++r) { sA[r] = 0.f; sB[r] = 0.f; }
            __builtin_amdgcn_s_setprio(1);
#pragma unroll
            for (int s = 0; s < 4; ++s) {
                const int g8 = ((2 * s + hi) ^ swz) * 8;
                s16x8 k0 = *(const s16x8*)&kc[qlane * 64 + g8];
                s16x8 k1 = *(const s16x8*)&kc[(qlane + 32) * 64 + g8];
                sA = __builtin_amdgcn_mfma_f32_32x32x16_bf16(k0, qf[s], sA, 0, 0, 0);
                sB = __builtin_amdgcn_mfma_f32_32x32x16_bf16(k1, qf[s], sB, 0, 0, 0);
            }
            __builtin_amdgcn_s_setprio(0);

            // ---- causal mask (only near-diagonal tiles)
            if (jt * 64 + 63 > q0 + w * 32) {
#pragma unroll
                for (int r = 0; r < 16; ++r) {
                    int kv = jt * 64 + (r & 3) + 8 * (r >> 2) + 4 * hi;
                    if (kv > qrow_g)      sA[r] = -INFINITY;
                    if (kv + 32 > qrow_g) sB[r] = -INFINITY;
                }
            }
            // ---- online softmax, in-register (q = lane&31)
            float pm = -INFINITY;
#pragma unroll
            for (int r = 0; r < 16; ++r) pm = fmaxf(pm, fmaxf(sA[r], sB[r]));
            pm = fmaxf(pm, __shfl_xor(pm, 32));
            float nm = fmaxf(m_i, pm);
            float sc = exp2f(m_i - nm);
            m_i = nm;
            float ps = 0.f;
#pragma unroll
            for (int r = 0; r < 16; ++r) {
                sA[r] = exp2f(sA[r] - nm); ps += sA[r];
                sB[r] = exp2f(sB[r] - nm); ps += sB[r];
            }
            ps += __shfl_xor(ps, 32);
            l_i = l_i * sc + ps;
#pragma unroll
            for (int r = 0; r < 16; ++r) { o0[r] *= sc; o1[r] *= sc; }

            // ---- pack P (C/D layout) -> 4 MFMA B-frags via cvt_pk + shfl
            s16x8 pf[4];
            auto packsub = [&](const f32x16& sv, s16x8* out) {
#pragma unroll
                for (int t = 0; t < 2; ++t) {
                    unsigned X = cvtpk(sv[8 * t + 0], sv[8 * t + 1]);
                    unsigned Z = cvtpk(sv[8 * t + 2], sv[8 * t + 3]);
                    unsigned Y = cvtpk(sv[8 * t + 4], sv[8 * t + 5]);
                    unsigned W = cvtpk(sv[8 * t + 6], sv[8 * t + 7]);
                    unsigned U0 = hi ? Y : X, V0 = hi ? X : Y;
                    unsigned U1 = hi ? W : Z, V1 = hi ? Z : W;
                    unsigned S0 = (unsigned)__shfl_xor((int)V0, 32);
                    unsigned S1 = (unsigned)__shfl_xor((int)V1, 32);
                    union { unsigned u[4]; s16x8 v; } fr;
                    fr.u[0] = hi ? S0 : U0;
                    fr.u[1] = hi ? S1 : U1;
                    fr.u[2] = hi ? U0 : S0;
                    fr.u[3] = hi ? U1 : S1;
                    out[t] = fr.v;
                }
            };
            packsub(sA, pf);
            packsub(sB, pf + 2);

            // ---- O^T += V^T P^T : frag t covers kv = 16t + 8hi + [0,8)
            __builtin_amdgcn_s_setprio(1);
#pragma unroll
            for (int t = 0; t < 4; ++t) {
                const int g8 = ((2 * t + hi) ^ swz) * 8;
                s16x8 v0 = *(const s16x8*)&vc[qlane * 64 + g8];
                s16x8 v1 = *(const s16x8*)&vc[(qlane + 32) * 64 + g8];
                o0 = __builtin_amdgcn_mfma_f32_32x32x16_bf16(v0, pf[t], o0, 0, 0, 0);
                o1 = __builtin_amdgcn_mfma_f32_32x32x16_bf16(v1, pf[t], o1, 0, 0, 0);
            }
            __builtin_amdgcn_s_setprio(0);
        }
        asm volatile("" ::: "memory");
        __builtin_amdgcn_s_barrier();              // all waves done reading cur
    }
#undef STAGE

    // ---- normalize + write: lane owns q-row qrow_g; d = (r&3)+8*(r>>2)+4hi(+32)
    float inv = 1.f / l_i;
    u16* yrow = y + ((size_t)(b * Tlen) + qrow_g) * Cdim + h * Dh;
#pragma unroll
    for (int g2 = 0; g2 < 4; ++g2) {
        u32x2 st;
        st[0] = cvtpk(o0[4 * g2 + 0] * inv, o0[4 * g2 + 1] * inv);
        st[1] = cvtpk(o0[4 * g2 + 2] * inv, o0[4 * g2 + 3] * inv);
        *(u32x2*)(yrow + 8 * g2 + 4 * hi) = st;
        st[0] = cvtpk(o1[4 * g2 + 0] * inv, o1[4 * g2 + 1] * inv);
        st[1] = cvtpk(o1[4 * g2 + 2] * inv, o1[4 * g2 + 3] * inv);
        *(u32x2*)(yrow + 32 + 8 * g2 + 4 * hi) = st;
    }
}

extern "C" void kernel_launch(void* const* d_in, const int* in_sizes, int n_in,
                              void* d_out, int out_size, void* d_ws, size_t ws_size,
                              hipStream_t stream) {
    const float* x  = (const float*)d_in[0];
    const float* Wq = (const float*)d_in[1];
    const float* bq = (const float*)d_in[2];
    const float* Wk = (const float*)d_in[3];
    const float* bk = (const float*)d_in[4];
    const float* Wv = (const float*)d_in[5];
    const float* bv = (const float*)d_in[6];
    const float* Wp = (const float*)d_in[7];
    const float* bp = (const float*)d_in[8];
    float* out = (float*)d_out;

    const size_t plane = (size_t)Mtot * Cdim;   // 8M elems
    const size_t wsz   = (size_t)Cdim * Cdim;   // 1M elems
    u16* xb    = (u16*)d_ws;
    u16* wqkvb = xb + plane;                    // Wq|Wk|Wv
    u16* wpb   = wqkvb + 3 * wsz;
    u16* qb    = wpb + wsz;                     // q,k planes contiguous
    u16* kb    = qb + plane;
    u16* vtb   = kb + plane;                    // V^T plane [B][H*D][T]

    cvt_bf16<<<plane / 2048, 256, 0, stream>>>(x, xb);
    cvt_bf16<<<wsz / 2048, 256, 0, stream>>>(Wq, wqkvb);
    cvt_bf16<<<wsz / 2048, 256, 0, stream>>>(Wk, wqkvb + wsz);
    cvt_bf16<<<wsz / 2048, 256, 0, stream>>>(Wv, wqkvb + 2 * wsz);
    cvt_bf16<<<wsz / 2048, 256, 0, stream>>>(Wp, wpb);

    gemm_qkv<<<dim3(Mtot / 128, 3 * Cdim / 128), 256, 0, stream>>>(
        xb, wqkvb, bq, bk, bv, qb, vtb);

    attn_mfma<<<dim3(1024), 256, 0, stream>>>(qb, kb, vtb, qb);

    gemm_proj<<<dim3(Mtot / 128, Cdim / 128), 256, 0, stream>>>(qb, wpb, bp, out);
}

// Round 6
// 213.323 us; speedup vs baseline: 15.1567x; 1.0026x over previous
//
#include <hip/hip_runtime.h>
#include <hip/hip_bf16.h>
#include <math.h>

static constexpr int Bn = 4, Tlen = 2048, Cdim = 1024, Hn = 16, Dh = 64;
static constexpr int Mtot = Bn * Tlen;

typedef __attribute__((ext_vector_type(8)))  short    s16x8;
typedef __attribute__((ext_vector_type(4)))  float    f32x4;
typedef __attribute__((ext_vector_type(16))) float    f32x16;
typedef __attribute__((ext_vector_type(2)))  unsigned u32x2;
typedef unsigned short u16;

// scale folded into Q: (1/sqrt(64)) * log2(e)
#define QSCALE 0.18033688011112042f

__device__ __forceinline__ u16 f2bf(float f) {
    union { float f; unsigned u; } x; x.f = f;
    unsigned r = x.u + 0x7FFFu + ((x.u >> 16) & 1u);   // RNE
    return (u16)(r >> 16);
}
__device__ __forceinline__ unsigned cvtpk(float lo, float hi) {
    unsigned r;
    asm("v_cvt_pk_bf16_f32 %0, %1, %2" : "=v"(r) : "v"(lo), "v"(hi));
    return r;
}
__device__ __forceinline__ void gload_lds16(const void* g, void* l) {
    __builtin_amdgcn_global_load_lds(
        (const __attribute__((address_space(1))) void*)g,
        (__attribute__((address_space(3))) void*)l, 16, 0, 0);
}

// ---------------- fp32 -> bf16 convert (vectorized) ----------------
__global__ __launch_bounds__(256) void cvt_bf16(const float* __restrict__ in,
                                                u16* __restrict__ out) {
    size_t i = (size_t)(blockIdx.x * 256 + threadIdx.x) * 8;
    float4 a = *(const float4*)(in + i);
    float4 b = *(const float4*)(in + i + 4);
    s16x8 o;
    o[0] = (short)f2bf(a.x); o[1] = (short)f2bf(a.y);
    o[2] = (short)f2bf(a.z); o[3] = (short)f2bf(a.w);
    o[4] = (short)f2bf(b.x); o[5] = (short)f2bf(b.y);
    o[6] = (short)f2bf(b.z); o[7] = (short)f2bf(b.w);
    *(s16x8*)(out + i) = o;
}

// ---------------- fused QKV GEMM: A[8192,1024] x Wqkv[3072,1024]^T ----------------
// q plane scaled by QSCALE; v plane written TRANSPOSED to vt [B, H*D, T].
__global__ __launch_bounds__(256) void gemm_qkv(const u16* __restrict__ A,
                                                const u16* __restrict__ B,
                                                const float* __restrict__ bq,
                                                const float* __restrict__ bk,
                                                const float* __restrict__ bv,
                                                u16* __restrict__ qkbase,
                                                u16* __restrict__ vt) {
    constexpr int K = Cdim, N = Cdim;
    __shared__ u16 As[128 * 32];
    __shared__ u16 Bs[128 * 32];
    // bijective XCD swizzle: 1536 blocks = 8 * 192
    const int f = blockIdx.y * gridDim.x + blockIdx.x;
    const int f2 = (f & 7) * ((int)(gridDim.x * gridDim.y) >> 3) + (f >> 3);
    const int bxs = f2 & 63, bys = f2 >> 6;

    const int tid = threadIdx.x, lane = tid & 63, w = tid >> 6;
    const int m0 = bxs * 128, n0g = bys * 128;
    const int which = n0g >> 10, n0 = n0g & 1023;
    const float* bias = which == 0 ? bq : (which == 1 ? bk : bv);
    const float osc = which == 0 ? QSCALE : 1.0f;
    const int wm = w >> 1, wn = w & 1;
    const int rowA = lane & 15, kg = lane >> 4;
    const int srow = lane >> 2, sc4 = (lane & 3) * 8;

    f32x4 acc[4][4] = {};
    const u16* Abase = A + (size_t)m0 * K;
    const u16* Bbase = B + (size_t)n0g * K;

    for (int k0 = 0; k0 < K; k0 += 32) {
        __syncthreads();
#pragma unroll
        for (int i = 0; i < 2; ++i) {
            int r0 = w * 32 + i * 16;
            gload_lds16(Abase + (size_t)(r0 + srow) * K + k0 + sc4, As + r0 * 32);
            gload_lds16(Bbase + (size_t)(r0 + srow) * K + k0 + sc4, Bs + r0 * 32);
        }
        asm volatile("s_waitcnt vmcnt(0)" ::: "memory");
        __syncthreads();

        s16x8 af[4], bfr[4];
#pragma unroll
        for (int mf = 0; mf < 4; ++mf)
            af[mf] = *(const s16x8*)&As[(wm * 64 + mf * 16 + rowA) * 32 + kg * 8];
#pragma unroll
        for (int nf = 0; nf < 4; ++nf)
            bfr[nf] = *(const s16x8*)&Bs[(wn * 64 + nf * 16 + rowA) * 32 + kg * 8];
#pragma unroll
        for (int mf = 0; mf < 4; ++mf)
#pragma unroll
            for (int nf = 0; nf < 4; ++nf)
                acc[mf][nf] = __builtin_amdgcn_mfma_f32_16x16x32_bf16(
                    af[mf], bfr[nf], acc[mf][nf], 0, 0, 0);
    }

    float bb[4];
#pragma unroll
    for (int nf = 0; nf < 4; ++nf) bb[nf] = bias[n0 + wn * 64 + nf * 16 + rowA];

    if (which < 2) {
        u16* C = qkbase + (size_t)which * ((size_t)Mtot * Cdim);
#pragma unroll
        for (int mf = 0; mf < 4; ++mf)
#pragma unroll
            for (int nf = 0; nf < 4; ++nf)
#pragma unroll
                for (int r = 0; r < 4; ++r) {
                    float val = (acc[mf][nf][r] + bb[nf]) * osc;
                    size_t row = m0 + wm * 64 + mf * 16 + kg * 4 + r;
                    size_t col = n0 + wn * 64 + nf * 16 + rowA;
                    C[row * N + col] = f2bf(val);
                }
    } else {
        // V plane -> write transposed: vt[b*1024 + (h*64+d)][t], 4 consecutive t per frag
#pragma unroll
        for (int mf = 0; mf < 4; ++mf)
#pragma unroll
            for (int nf = 0; nf < 4; ++nf) {
                int hd = n0 + wn * 64 + nf * 16 + rowA;
                size_t row0 = m0 + wm * 64 + mf * 16 + kg * 4;
                int bi = (int)(row0 >> 11), t0 = (int)(row0 & 2047);
                union { u16 h[4]; u32x2 d; } pk;
#pragma unroll
                for (int r = 0; r < 4; ++r) pk.h[r] = f2bf(acc[mf][nf][r] + bb[nf]);
                *(u32x2*)(vt + ((size_t)bi * 1024 + hd) * Tlen + t0) = pk.d;
            }
    }
}

// ---------------- out-proj GEMM: bf16 A,B -> fp32 out ----------------
__global__ __launch_bounds__(256) void gemm_proj(const u16* __restrict__ A,
                                                 const u16* __restrict__ B,
                                                 const float* __restrict__ bias,
                                                 float* __restrict__ C) {
    constexpr int K = Cdim, N = Cdim;
    __shared__ u16 As[128 * 32];
    __shared__ u16 Bs[128 * 32];
    const int f = blockIdx.y * gridDim.x + blockIdx.x;    // 512 = 8 * 64
    const int f2 = (f & 7) * ((int)(gridDim.x * gridDim.y) >> 3) + (f >> 3);
    const int bxs = f2 & 63, bys = f2 >> 6;

    const int tid = threadIdx.x, lane = tid & 63, w = tid >> 6;
    const int m0 = bxs * 128, n0 = bys * 128;
    const int wm = w >> 1, wn = w & 1;
    const int rowA = lane & 15, kg = lane >> 4;
    const int srow = lane >> 2, sc4 = (lane & 3) * 8;

    f32x4 acc[4][4] = {};
    const u16* Abase = A + (size_t)m0 * K;
    const u16* Bbase = B + (size_t)n0 * K;

    for (int k0 = 0; k0 < K; k0 += 32) {
        __syncthreads();
#pragma unroll
        for (int i = 0; i < 2; ++i) {
            int r0 = w * 32 + i * 16;
            gload_lds16(Abase + (size_t)(r0 + srow) * K + k0 + sc4, As + r0 * 32);
            gload_lds16(Bbase + (size_t)(r0 + srow) * K + k0 + sc4, Bs + r0 * 32);
        }
        asm volatile("s_waitcnt vmcnt(0)" ::: "memory");
        __syncthreads();

        s16x8 af[4], bfr[4];
#pragma unroll
        for (int mf = 0; mf < 4; ++mf)
            af[mf] = *(const s16x8*)&As[(wm * 64 + mf * 16 + rowA) * 32 + kg * 8];
#pragma unroll
        for (int nf = 0; nf < 4; ++nf)
            bfr[nf] = *(const s16x8*)&Bs[(wn * 64 + nf * 16 + rowA) * 32 + kg * 8];
#pragma unroll
        for (int mf = 0; mf < 4; ++mf)
#pragma unroll
            for (int nf = 0; nf < 4; ++nf)
                acc[mf][nf] = __builtin_amdgcn_mfma_f32_16x16x32_bf16(
                    af[mf], bfr[nf], acc[mf][nf], 0, 0, 0);
    }

    float bb[4];
#pragma unroll
    for (int nf = 0; nf < 4; ++nf) bb[nf] = bias[n0 + wn * 64 + nf * 16 + rowA];
#pragma unroll
    for (int mf = 0; mf < 4; ++mf)
#pragma unroll
        for (int nf = 0; nf < 4; ++nf)
#pragma unroll
            for (int r = 0; r < 4; ++r) {
                size_t row = m0 + wm * 64 + mf * 16 + kg * 4 + r;
                size_t col = n0 + wn * 64 + nf * 16 + rowA;
                C[row * N + col] = acc[mf][nf][r] + bb[nf];
            }
}

// ---------------- MFMA flash attention, 32x32 swapped-operand ----------------
// 256 threads = 4 waves, 128 q-rows/block; wave w owns rows q0+w*32+[0,32).
// Flat 1024-block grid, LPT order (long qt first). Counted-vmcnt double buffer
// with raw s_barrier (no vmcnt(0) drain in steady state).
__global__ __launch_bounds__(256, 4) void attn_mfma(const u16* __restrict__ q,
                                                    const u16* __restrict__ k,
                                                    const u16* __restrict__ vt,
                                                    u16* y) {
    const int fid = blockIdx.x;
    const int qt = 15 - (fid >> 6);                 // LPT: qt=15 dispatched first
    const int rem = fid & 63;
    const int h = rem & 15, b = rem >> 4;
    const int tid = threadIdx.x, lane = tid & 63, w = tid >> 6;
    const int qlane = lane & 31, hi = lane >> 5;
    __shared__ u16 Ks[2][64 * 64];
    __shared__ u16 Vs[2][64 * 64];

    const int q0 = qt * 128;
    const int qrow_g = q0 + w * 32 + qlane;

    // Q fragments to registers: step s covers d = 16s + 8*hi + [0,8)
    const u16* qrow = q + ((size_t)(b * Tlen) + qrow_g) * Cdim + h * Dh;
    s16x8 qf[4];
#pragma unroll
    for (int s = 0; s < 4; ++s)
        qf[s] = *(const s16x8*)(qrow + s * 16 + hi * 8);

    const u16* kbase = k + ((size_t)(b * Tlen)) * Cdim + h * Dh;
    const u16* vbase = vt + ((size_t)(b * Hn + h)) * (size_t)(Dh * Tlen);

    // staging: thread stages granules tid and tid+256 of each 512-granule tile
    const int g0row = tid >> 3;
    const int g1row = g0row + 32;
    const int gc0 = (((tid) & 7) ^ (g0row & 7)) * 8;   // pre-swizzled source col
    const int gc1 = (((tid) & 7) ^ (g1row & 7)) * 8;

#define STAGE(JT, BUF)                                                              \
    do {                                                                            \
        const u16* kb2 = kbase + (size_t)((JT) * 64) * Cdim;                        \
        const u16* vb2 = vbase + (JT) * 64;                                         \
        gload_lds16(kb2 + (size_t)g0row * Cdim + gc0, &Ks[BUF][w * 512]);           \
        gload_lds16(kb2 + (size_t)g1row * Cdim + gc1, &Ks[BUF][2048 + w * 512]);    \
        gload_lds16(vb2 + (size_t)g0row * Tlen + gc0, &Vs[BUF][w * 512]);           \
        gload_lds16(vb2 + (size_t)g1row * Tlen + gc1, &Vs[BUF][2048 + w * 512]);    \
    } while (0)

    STAGE(0, 0);

    f32x16 o0, o1;
#pragma unroll
    for (int r = 0; r < 16; ++r) { o0[r] = 0.f; o1[r] = 0.f; }
    float m_i = -INFINITY, l_i = 0.f;

    const int njt = 2 * qt + 2;
    const int jtmax = 2 * qt + (w >> 1);          // last tile this wave needs
    const int swz = (qlane & 7);

    for (int jt = 0; jt < njt; ++jt) {
        const int cur = jt & 1;
        if (jt + 1 < njt) {
            STAGE(jt + 1, cur ^ 1);
            asm volatile("s_waitcnt vmcnt(4)" ::: "memory");   // cur landed, next in flight
        } else {
            asm volatile("s_waitcnt vmcnt(0)" ::: "memory");
        }
        __builtin_amdgcn_s_barrier();              // all waves' cur data visible

        if (jt <= jtmax) {
            const u16* kc = &Ks[cur][0];
            const u16* vc = &Vs[cur][0];
            // ---- S^T = K Q^T : two 32-kv subtiles
            f32x16 sA, sB;
#pragma unroll
            for (int r = 0; r < 16; ++r) { sA[r] = 0.f; sB[r] = 0.f; }
            __builtin_amdgcn_s_setprio(1);
#pragma unroll
            for (int s = 0; s < 4; ++s) {
                const int g8 = ((2 * s + hi) ^ swz) * 8;
                s16x8 k0 = *(const s16x8*)&kc[qlane * 64 + g8];
                s16x8 k1 = *(const s16x8*)&kc[(qlane + 32) * 64 + g8];
                sA = __builtin_amdgcn_mfma_f32_32x32x16_bf16(k0, qf[s], sA, 0, 0, 0);
                sB = __builtin_amdgcn_mfma_f32_32x32x16_bf16(k1, qf[s], sB, 0, 0, 0);
            }
            __builtin_amdgcn_s_setprio(0);

            // ---- causal mask (only near-diagonal tiles)
            if (jt * 64 + 63 > q0 + w * 32) {
#pragma unroll
                for (int r = 0; r < 16; ++r) {
                    int kv = jt * 64 + (r & 3) + 8 * (r >> 2) + 4 * hi;
                    if (kv > qrow_g)      sA[r] = -INFINITY;
                    if (kv + 32 > qrow_g) sB[r] = -INFINITY;
                }
            }
            // ---- online softmax, in-register (q = lane&31)
            float pm = -INFINITY;
#pragma unroll
            for (int r = 0; r < 16; ++r) pm = fmaxf(pm, fmaxf(sA[r], sB[r]));
            pm = fmaxf(pm, __shfl_xor(pm, 32));
            float nm = fmaxf(m_i, pm);
            float sc = exp2f(m_i - nm);
            m_i = nm;
            float ps = 0.f;
#pragma unroll
            for (int r = 0; r < 16; ++r) {
                sA[r] = exp2f(sA[r] - nm); ps += sA[r];
                sB[r] = exp2f(sB[r] - nm); ps += sB[r];
            }
            ps += __shfl_xor(ps, 32);
            l_i = l_i * sc + ps;
#pragma unroll
            for (int r = 0; r < 16; ++r) { o0[r] *= sc; o1[r] *= sc; }

            // ---- pack P (C/D layout) -> 4 MFMA B-frags via cvt_pk + shfl
            s16x8 pf[4];
            auto packsub = [&](const f32x16& sv, s16x8* out) {
#pragma unroll
                for (int t = 0; t < 2; ++t) {
                    unsigned X = cvtpk(sv[8 * t + 0], sv[8 * t + 1]);
                    unsigned Z = cvtpk(sv[8 * t + 2], sv[8 * t + 3]);
                    unsigned Y = cvtpk(sv[8 * t + 4], sv[8 * t + 5]);
                    unsigned W = cvtpk(sv[8 * t + 6], sv[8 * t + 7]);
                    unsigned U0 = hi ? Y : X, V0 = hi ? X : Y;
                    unsigned U1 = hi ? W : Z, V1 = hi ? Z : W;
                    unsigned S0 = (unsigned)__shfl_xor((int)V0, 32);
                    unsigned S1 = (unsigned)__shfl_xor((int)V1, 32);
                    union { unsigned u[4]; s16x8 v; } fr;
                    fr.u[0] = hi ? S0 : U0;
                    fr.u[1] = hi ? S1 : U1;
                    fr.u[2] = hi ? U0 : S0;
                    fr.u[3] = hi ? U1 : S1;
                    out[t] = fr.v;
                }
            };
            packsub(sA, pf);
            packsub(sB, pf + 2);

            // ---- O^T += V^T P^T : frag t covers kv = 16t + 8hi + [0,8)
            __builtin_amdgcn_s_setprio(1);
#pragma unroll
            for (int t = 0; t < 4; ++t) {
                const int g8 = ((2 * t + hi) ^ swz) * 8;
                s16x8 v0 = *(const s16x8*)&vc[qlane * 64 + g8];
                s16x8 v1 = *(const s16x8*)&vc[(qlane + 32) * 64 + g8];
                o0 = __builtin_amdgcn_mfma_f32_32x32x16_bf16(v0, pf[t], o0, 0, 0, 0);
                o1 = __builtin_amdgcn_mfma_f32_32x32x16_bf16(v1, pf[t], o1, 0, 0, 0);
            }
            __builtin_amdgcn_s_setprio(0);
        }
        asm volatile("" ::: "memory");
        __builtin_amdgcn_s_barrier();              // all waves done reading cur
    }
#undef STAGE

    // ---- normalize + write: lane owns q-row qrow_g; d = (r&3)+8*(r>>2)+4hi(+32)
    float inv = 1.f / l_i;
    u16* yrow = y + ((size_t)(b * Tlen) + qrow_g) * Cdim + h * Dh;
#pragma unroll
    for (int g2 = 0; g2 < 4; ++g2) {
        u32x2 st;
        st[0] = cvtpk(o0[4 * g2 + 0] * inv, o0[4 * g2 + 1] * inv);
        st[1] = cvtpk(o0[4 * g2 + 2] * inv, o0[4 * g2 + 3] * inv);
        *(u32x2*)(yrow + 8 * g2 + 4 * hi) = st;
        st[0] = cvtpk(o1[4 * g2 + 0] * inv, o1[4 * g2 + 1] * inv);
        st[1] = cvtpk(o1[4 * g2 + 2] * inv, o1[4 * g2 + 3] * inv);
        *(u32x2*)(yrow + 32 + 8 * g2 + 4 * hi) = st;
    }
}

extern "C" void kernel_launch(void* const* d_in, const int* in_sizes, int n_in,
                              void* d_out, int out_size, void* d_ws, size_t ws_size,
                              hipStream_t stream) {
    const float* x  = (const float*)d_in[0];
    const float* Wq = (const float*)d_in[1];
    const float* bq = (const float*)d_in[2];
    const float* Wk = (const float*)d_in[3];
    const float* bk = (const float*)d_in[4];
    const float* Wv = (const float*)d_in[5];
    const float* bv = (const float*)d_in[6];
    const float* Wp = (const float*)d_in[7];
    const float* bp = (const float*)d_in[8];
    float* out = (float*)d_out;

    const size_t plane = (size_t)Mtot * Cdim;   // 8M elems
    const size_t wsz   = (size_t)Cdim * Cdim;   // 1M elems
    u16* xb    = (u16*)d_ws;
    u16* wqkvb = xb + plane;                    // Wq|Wk|Wv
    u16* wpb   = wqkvb + 3 * wsz;
    u16* qb    = wpb + wsz;                     // q,k planes contiguous
    u16* kb    = qb + plane;
    u16* vtb   = kb + plane;                    // V^T plane [B][H*D][T]

    cvt_bf16<<<plane / 2048, 256, 0, stream>>>(x, xb);
    cvt_bf16<<<wsz / 2048, 256, 0, stream>>>(Wq, wqkvb);
    cvt_bf16<<<wsz / 2048, 256, 0, stream>>>(Wk, wqkvb + wsz);
    cvt_bf16<<<wsz / 2048, 256, 0, stream>>>(Wv, wqkvb + 2 * wsz);
    cvt_bf16<<<wsz / 2048, 256, 0, stream>>>(Wp, wpb);

    gemm_qkv<<<dim3(Mtot / 128, 3 * Cdim / 128), 256, 0, stream>>>(
        xb, wqkvb, bq, bk, bv, qb, vtb);

    attn_mfma<<<dim3(1024), 256, 0, stream>>>(qb, kb, vtb, qb);

    gemm_proj<<<dim3(Mtot / 128, Cdim / 128), 256, 0, stream>>>(qb, wpb, bp, out);
}

// Round 7
// 212.966 us; speedup vs baseline: 15.1822x; 1.0017x over previous
//
#include <hip/hip_runtime.h>
#include <hip/hip_bf16.h>
#include <math.h>

static constexpr int Bn = 4, Tlen = 2048, Cdim = 1024, Hn = 16, Dh = 64;
static constexpr int Mtot = Bn * Tlen;

typedef __attribute__((ext_vector_type(8)))  short    s16x8;
typedef __attribute__((ext_vector_type(4)))  float    f32x4;
typedef __attribute__((ext_vector_type(16))) float    f32x16;
typedef __attribute__((ext_vector_type(2)))  unsigned u32x2;
typedef unsigned short u16;

// scale folded into Q: (1/sqrt(64)) * log2(e)
#define QSCALE 0.18033688011112042f

__device__ __forceinline__ u16 f2bf(float f) {
    union { float f; unsigned u; } x; x.f = f;
    unsigned r = x.u + 0x7FFFu + ((x.u >> 16) & 1u);   // RNE
    return (u16)(r >> 16);
}
__device__ __forceinline__ unsigned cvtpk(float lo, float hi) {
    unsigned r;
    asm("v_cvt_pk_bf16_f32 %0, %1, %2" : "=v"(r) : "v"(lo), "v"(hi));
    return r;
}
__device__ __forceinline__ void gload_lds16(const void* g, void* l) {
    __builtin_amdgcn_global_load_lds(
        (const __attribute__((address_space(1))) void*)g,
        (__attribute__((address_space(3))) void*)l, 16, 0, 0);
}

// ---------------- fp32 -> bf16 convert (vectorized) ----------------
__global__ __launch_bounds__(256) void cvt_bf16(const float* __restrict__ in,
                                                u16* __restrict__ out) {
    size_t i = (size_t)(blockIdx.x * 256 + threadIdx.x) * 8;
    float4 a = *(const float4*)(in + i);
    float4 b = *(const float4*)(in + i + 4);
    s16x8 o;
    o[0] = (short)f2bf(a.x); o[1] = (short)f2bf(a.y);
    o[2] = (short)f2bf(a.z); o[3] = (short)f2bf(a.w);
    o[4] = (short)f2bf(b.x); o[5] = (short)f2bf(b.y);
    o[6] = (short)f2bf(b.z); o[7] = (short)f2bf(b.w);
    *(s16x8*)(out + i) = o;
}

// ---------------- fused QKV GEMM: A[8192,1024] x Wqkv[3072,1024]^T ----------------
// q plane scaled by QSCALE; v plane written TRANSPOSED to vt [B, H*D, T].
__global__ __launch_bounds__(256) void gemm_qkv(const u16* __restrict__ A,
                                                const u16* __restrict__ B,
                                                const float* __restrict__ bq,
                                                const float* __restrict__ bk,
                                                const float* __restrict__ bv,
                                                u16* __restrict__ qkbase,
                                                u16* __restrict__ vt) {
    constexpr int K = Cdim, N = Cdim;
    __shared__ u16 As[128 * 32];
    __shared__ u16 Bs[128 * 32];
    // bijective XCD swizzle: 1536 blocks = 8 * 192
    const int f = blockIdx.y * gridDim.x + blockIdx.x;
    const int f2 = (f & 7) * ((int)(gridDim.x * gridDim.y) >> 3) + (f >> 3);
    const int bxs = f2 & 63, bys = f2 >> 6;

    const int tid = threadIdx.x, lane = tid & 63, w = tid >> 6;
    const int m0 = bxs * 128, n0g = bys * 128;
    const int which = n0g >> 10, n0 = n0g & 1023;
    const float* bias = which == 0 ? bq : (which == 1 ? bk : bv);
    const float osc = which == 0 ? QSCALE : 1.0f;
    const int wm = w >> 1, wn = w & 1;
    const int rowA = lane & 15, kg = lane >> 4;
    const int srow = lane >> 2, sc4 = (lane & 3) * 8;

    f32x4 acc[4][4] = {};
    const u16* Abase = A + (size_t)m0 * K;
    const u16* Bbase = B + (size_t)n0g * K;

    for (int k0 = 0; k0 < K; k0 += 32) {
        __syncthreads();
#pragma unroll
        for (int i = 0; i < 2; ++i) {
            int r0 = w * 32 + i * 16;
            gload_lds16(Abase + (size_t)(r0 + srow) * K + k0 + sc4, As + r0 * 32);
            gload_lds16(Bbase + (size_t)(r0 + srow) * K + k0 + sc4, Bs + r0 * 32);
        }
        asm volatile("s_waitcnt vmcnt(0)" ::: "memory");
        __syncthreads();

        s16x8 af[4], bfr[4];
#pragma unroll
        for (int mf = 0; mf < 4; ++mf)
            af[mf] = *(const s16x8*)&As[(wm * 64 + mf * 16 + rowA) * 32 + kg * 8];
#pragma unroll
        for (int nf = 0; nf < 4; ++nf)
            bfr[nf] = *(const s16x8*)&Bs[(wn * 64 + nf * 16 + rowA) * 32 + kg * 8];
#pragma unroll
        for (int mf = 0; mf < 4; ++mf)
#pragma unroll
            for (int nf = 0; nf < 4; ++nf)
                acc[mf][nf] = __builtin_amdgcn_mfma_f32_16x16x32_bf16(
                    af[mf], bfr[nf], acc[mf][nf], 0, 0, 0);
    }

    float bb[4];
#pragma unroll
    for (int nf = 0; nf < 4; ++nf) bb[nf] = bias[n0 + wn * 64 + nf * 16 + rowA];

    if (which < 2) {
        u16* C = qkbase + (size_t)which * ((size_t)Mtot * Cdim);
#pragma unroll
        for (int mf = 0; mf < 4; ++mf)
#pragma unroll
            for (int nf = 0; nf < 4; ++nf)
#pragma unroll
                for (int r = 0; r < 4; ++r) {
                    float val = (acc[mf][nf][r] + bb[nf]) * osc;
                    size_t row = m0 + wm * 64 + mf * 16 + kg * 4 + r;
                    size_t col = n0 + wn * 64 + nf * 16 + rowA;
                    C[row * N + col] = f2bf(val);
                }
    } else {
        // V plane -> write transposed: vt[b*1024 + (h*64+d)][t], 4 consecutive t per frag
#pragma unroll
        for (int mf = 0; mf < 4; ++mf)
#pragma unroll
            for (int nf = 0; nf < 4; ++nf) {
                int hd = n0 + wn * 64 + nf * 16 + rowA;
                size_t row0 = m0 + wm * 64 + mf * 16 + kg * 4;
                int bi = (int)(row0 >> 11), t0 = (int)(row0 & 2047);
                union { u16 h[4]; u32x2 d; } pk;
#pragma unroll
                for (int r = 0; r < 4; ++r) pk.h[r] = f2bf(acc[mf][nf][r] + bb[nf]);
                *(u32x2*)(vt + ((size_t)bi * 1024 + hd) * Tlen + t0) = pk.d;
            }
    }
}

// ---------------- out-proj GEMM: bf16 A,B -> fp32 out ----------------
__global__ __launch_bounds__(256) void gemm_proj(const u16* __restrict__ A,
                                                 const u16* __restrict__ B,
                                                 const float* __restrict__ bias,
                                                 float* __restrict__ C) {
    constexpr int K = Cdim, N = Cdim;
    __shared__ u16 As[128 * 32];
    __shared__ u16 Bs[128 * 32];
    const int f = blockIdx.y * gridDim.x + blockIdx.x;    // 512 = 8 * 64
    const int f2 = (f & 7) * ((int)(gridDim.x * gridDim.y) >> 3) + (f >> 3);
    const int bxs = f2 & 63, bys = f2 >> 6;

    const int tid = threadIdx.x, lane = tid & 63, w = tid >> 6;
    const int m0 = bxs * 128, n0 = bys * 128;
    const int wm = w >> 1, wn = w & 1;
    const int rowA = lane & 15, kg = lane >> 4;
    const int srow = lane >> 2, sc4 = (lane & 3) * 8;

    f32x4 acc[4][4] = {};
    const u16* Abase = A + (size_t)m0 * K;
    const u16* Bbase = B + (size_t)n0 * K;

    for (int k0 = 0; k0 < K; k0 += 32) {
        __syncthreads();
#pragma unroll
        for (int i = 0; i < 2; ++i) {
            int r0 = w * 32 + i * 16;
            gload_lds16(Abase + (size_t)(r0 + srow) * K + k0 + sc4, As + r0 * 32);
            gload_lds16(Bbase + (size_t)(r0 + srow) * K + k0 + sc4, Bs + r0 * 32);
        }
        asm volatile("s_waitcnt vmcnt(0)" ::: "memory");
        __syncthreads();

        s16x8 af[4], bfr[4];
#pragma unroll
        for (int mf = 0; mf < 4; ++mf)
            af[mf] = *(const s16x8*)&As[(wm * 64 + mf * 16 + rowA) * 32 + kg * 8];
#pragma unroll
        for (int nf = 0; nf < 4; ++nf)
            bfr[nf] = *(const s16x8*)&Bs[(wn * 64 + nf * 16 + rowA) * 32 + kg * 8];
#pragma unroll
        for (int mf = 0; mf < 4; ++mf)
#pragma unroll
            for (int nf = 0; nf < 4; ++nf)
                acc[mf][nf] = __builtin_amdgcn_mfma_f32_16x16x32_bf16(
                    af[mf], bfr[nf], acc[mf][nf], 0, 0, 0);
    }

    float bb[4];
#pragma unroll
    for (int nf = 0; nf < 4; ++nf) bb[nf] = bias[n0 + wn * 64 + nf * 16 + rowA];
#pragma unroll
    for (int mf = 0; mf < 4; ++mf)
#pragma unroll
        for (int nf = 0; nf < 4; ++nf)
#pragma unroll
            for (int r = 0; r < 4; ++r) {
                size_t row = m0 + wm * 64 + mf * 16 + kg * 4 + r;
                size_t col = n0 + wn * 64 + nf * 16 + rowA;
                C[row * N + col] = acc[mf][nf][r] + bb[nf];
            }
}

// ---------------- MFMA flash attention, 32x32 swapped-operand ----------------
// 256 threads = 4 waves, 128 q-rows/block; wave w owns rows q0+w*32+[0,32).
// Flat 1024-block grid, LPT order (long qt first). Counted-vmcnt double buffer
// with raw s_barrier (no vmcnt(0) drain in steady state).
__global__ __launch_bounds__(256, 4) void attn_mfma(const u16* __restrict__ q,
                                                    const u16* __restrict__ k,
                                                    const u16* __restrict__ vt,
                                                    u16* y) {
    const int fid = blockIdx.x;
    const int qt = 15 - (fid >> 6);                 // LPT: qt=15 dispatched first
    const int rem = fid & 63;
    const int h = rem & 15, b = rem >> 4;
    const int tid = threadIdx.x, lane = tid & 63, w = tid >> 6;
    const int qlane = lane & 31, hi = lane >> 5;
    __shared__ u16 Ks[2][64 * 64];
    __shared__ u16 Vs[2][64 * 64];

    const int q0 = qt * 128;
    const int qrow_g = q0 + w * 32 + qlane;

    // Q fragments to registers: step s covers d = 16s + 8*hi + [0,8)
    const u16* qrow = q + ((size_t)(b * Tlen) + qrow_g) * Cdim + h * Dh;
    s16x8 qf[4];
#pragma unroll
    for (int s = 0; s < 4; ++s)
        qf[s] = *(const s16x8*)(qrow + s * 16 + hi * 8);

    const u16* kbase = k + ((size_t)(b * Tlen)) * Cdim + h * Dh;
    const u16* vbase = vt + ((size_t)(b * Hn + h)) * (size_t)(Dh * Tlen);

    // staging: thread stages granules tid and tid+256 of each 512-granule tile
    const int g0row = tid >> 3;
    const int g1row = g0row + 32;
    const int gc0 = (((tid) & 7) ^ (g0row & 7)) * 8;   // pre-swizzled source col
    const int gc1 = (((tid) & 7) ^ (g1row & 7)) * 8;

#define STAGE(JT, BUF)                                                              \
    do {                                                                            \
        const u16* kb2 = kbase + (size_t)((JT) * 64) * Cdim;                        \
        const u16* vb2 = vbase + (JT) * 64;                                         \
        gload_lds16(kb2 + (size_t)g0row * Cdim + gc0, &Ks[BUF][w * 512]);           \
        gload_lds16(kb2 + (size_t)g1row * Cdim + gc1, &Ks[BUF][2048 + w * 512]);    \
        gload_lds16(vb2 + (size_t)g0row * Tlen + gc0, &Vs[BUF][w * 512]);           \
        gload_lds16(vb2 + (size_t)g1row * Tlen + gc1, &Vs[BUF][2048 + w * 512]);    \
    } while (0)

    STAGE(0, 0);

    f32x16 o0, o1;
#pragma unroll
    for (int r = 0; r < 16; ++r) { o0[r] = 0.f; o1[r] = 0.f; }
    float m_i = -INFINITY, l_i = 0.f;

    const int njt = 2 * qt + 2;
    const int jtmax = 2 * qt + (w >> 1);          // last tile this wave needs
    const int swz = (qlane & 7);

    for (int jt = 0; jt < njt; ++jt) {
        const int cur = jt & 1;
        if (jt + 1 < njt) {
            STAGE(jt + 1, cur ^ 1);
            asm volatile("s_waitcnt vmcnt(4)" ::: "memory");   // cur landed, next in flight
        } else {
            asm volatile("s_waitcnt vmcnt(0)" ::: "memory");
        }
        __builtin_amdgcn_s_barrier();              // all waves' cur data visible

        if (jt <= jtmax) {
            const u16* kc = &Ks[cur][0];
            const u16* vc = &Vs[cur][0];
            // ---- S^T = K Q^T : two 32-kv subtiles
            f32x16 sA, sB;
#pragma unroll
            for (int r = 0; r < 16; ++r) { sA[r] = 0.f; sB[r] = 0.f; }
            __builtin_amdgcn_s_setprio(1);
#pragma unroll
            for (int s = 0; s < 4; ++s) {
                const int g8 = ((2 * s + hi) ^ swz) * 8;
                s16x8 k0 = *(const s16x8*)&kc[qlane * 64 + g8];
                s16x8 k1 = *(const s16x8*)&kc[(qlane + 32) * 64 + g8];
                sA = __builtin_amdgcn_mfma_f32_32x32x16_bf16(k0, qf[s], sA, 0, 0, 0);
                sB = __builtin_amdgcn_mfma_f32_32x32x16_bf16(k1, qf[s], sB, 0, 0, 0);
            }
            __builtin_amdgcn_s_setprio(0);

            // ---- causal mask (only near-diagonal tiles)
            if (jt * 64 + 63 > q0 + w * 32) {
#pragma unroll
                for (int r = 0; r < 16; ++r) {
                    int kv = jt * 64 + (r & 3) + 8 * (r >> 2) + 4 * hi;
                    if (kv > qrow_g)      sA[r] = -INFINITY;
                    if (kv + 32 > qrow_g) sB[r] = -INFINITY;
                }
            }
            // ---- online softmax, in-register (q = lane&31)
            float pm = -INFINITY;
#pragma unroll
            for (int r = 0; r < 16; ++r) pm = fmaxf(pm, fmaxf(sA[r], sB[r]));
            pm = fmaxf(pm, __shfl_xor(pm, 32));
            float nm = fmaxf(m_i, pm);
            float sc = exp2f(m_i - nm);
            m_i = nm;
            float ps = 0.f;
#pragma unroll
            for (int r = 0; r < 16; ++r) {
                sA[r] = exp2f(sA[r] - nm); ps += sA[r];
                sB[r] = exp2f(sB[r] - nm); ps += sB[r];
            }
            ps += __shfl_xor(ps, 32);
            l_i = l_i * sc + ps;
#pragma unroll
            for (int r = 0; r < 16; ++r) { o0[r] *= sc; o1[r] *= sc; }

            // ---- pack P (C/D layout) -> 4 MFMA B-frags via cvt_pk + shfl
            s16x8 pf[4];
            auto packsub = [&](const f32x16& sv, s16x8* out) {
#pragma unroll
                for (int t = 0; t < 2; ++t) {
                    unsigned X = cvtpk(sv[8 * t + 0], sv[8 * t + 1]);
                    unsigned Z = cvtpk(sv[8 * t + 2], sv[8 * t + 3]);
                    unsigned Y = cvtpk(sv[8 * t + 4], sv[8 * t + 5]);
                    unsigned W = cvtpk(sv[8 * t + 6], sv[8 * t + 7]);
                    unsigned U0 = hi ? Y : X, V0 = hi ? X : Y;
                    unsigned U1 = hi ? W : Z, V1 = hi ? Z : W;
                    unsigned S0 = (unsigned)__shfl_xor((int)V0, 32);
                    unsigned S1 = (unsigned)__shfl_xor((int)V1, 32);
                    union { unsigned u[4]; s16x8 v; } fr;
                    fr.u[0] = hi ? S0 : U0;
                    fr.u[1] = hi ? S1 : U1;
                    fr.u[2] = hi ? U0 : S0;
                    fr.u[3] = hi ? U1 : S1;
                    out[t] = fr.v;
                }
            };
            packsub(sA, pf);
            packsub(sB, pf + 2);

            // ---- O^T += V^T P^T : frag t covers kv = 16t + 8hi + [0,8)
            __builtin_amdgcn_s_setprio(1);
#pragma unroll
            for (int t = 0; t < 4; ++t) {
                const int g8 = ((2 * t + hi) ^ swz) * 8;
                s16x8 v0 = *(const s16x8*)&vc[qlane * 64 + g8];
                s16x8 v1 = *(const s16x8*)&vc[(qlane + 32) * 64 + g8];
                o0 = __builtin_amdgcn_mfma_f32_32x32x16_bf16(v0, pf[t], o0, 0, 0, 0);
                o1 = __builtin_amdgcn_mfma_f32_32x32x16_bf16(v1, pf[t], o1, 0, 0, 0);
            }
            __builtin_amdgcn_s_setprio(0);
        }
        asm volatile("" ::: "memory");
        __builtin_amdgcn_s_barrier();              // all waves done reading cur
    }
#undef STAGE

    // ---- normalize + write: lane owns q-row qrow_g; d = (r&3)+8*(r>>2)+4hi(+32)
    float inv = 1.f / l_i;
    u16* yrow = y + ((size_t)(b * Tlen) + qrow_g) * Cdim + h * Dh;
#pragma unroll
    for (int g2 = 0; g2 < 4; ++g2) {
        u32x2 st;
        st[0] = cvtpk(o0[4 * g2 + 0] * inv, o0[4 * g2 + 1] * inv);
        st[1] = cvtpk(o0[4 * g2 + 2] * inv, o0[4 * g2 + 3] * inv);
        *(u32x2*)(yrow + 8 * g2 + 4 * hi) = st;
        st[0] = cvtpk(o1[4 * g2 + 0] * inv, o1[4 * g2 + 1] * inv);
        st[1] = cvtpk(o1[4 * g2 + 2] * inv, o1[4 * g2 + 3] * inv);
        *(u32x2*)(yrow + 32 + 8 * g2 + 4 * hi) = st;
    }
}

extern "C" void kernel_launch(void* const* d_in, const int* in_sizes, int n_in,
                              void* d_out, int out_size, void* d_ws, size_t ws_size,
                              hipStream_t stream) {
    const float* x  = (const float*)d_in[0];
    const float* Wq = (const float*)d_in[1];
    const float* bq = (const float*)d_in[2];
    const float* Wk = (const float*)d_in[3];
    const float* bk = (const float*)d_in[4];
    const float* Wv = (const float*)d_in[5];
    const float* bv = (const float*)d_in[6];
    const float* Wp = (const float*)d_in[7];
    const float* bp = (const float*)d_in[8];
    float* out = (float*)d_out;

    const size_t plane = (size_t)Mtot * Cdim;   // 8M elems
    const size_t wsz   = (size_t)Cdim * Cdim;   // 1M elems
    u16* xb    = (u16*)d_ws;
    u16* wqkvb = xb + plane;                    // Wq|Wk|Wv
    u16* wpb   = wqkvb + 3 * wsz;
    u16* qb    = wpb + wsz;                     // q,k planes contiguous
    u16* kb    = qb + plane;
    u16* vtb   = kb + plane;                    // V^T plane [B][H*D][T]

    cvt_bf16<<<plane / 2048, 256, 0, stream>>>(x, xb);
    cvt_bf16<<<wsz / 2048, 256, 0, stream>>>(Wq, wqkvb);
    cvt_bf16<<<wsz / 2048, 256, 0, stream>>>(Wk, wqkvb + wsz);
    cvt_bf16<<<wsz / 2048, 256, 0, stream>>>(Wv, wqkvb + 2 * wsz);
    cvt_bf16<<<wsz / 2048, 256, 0, stream>>>(Wp, wpb);

    gemm_qkv<<<dim3(Mtot / 128, 3 * Cdim / 128), 256, 0, stream>>>(
        xb, wqkvb, bq, bk, bv, qb, vtb);

    attn_mfma<<<dim3(1024), 256, 0, stream>>>(qb, kb, vtb, qb);

    gemm_proj<<<dim3(Mtot / 128, Cdim / 128), 256, 0, stream>>>(qb, wpb, bp, out);
}

// Round 8
// 212.195 us; speedup vs baseline: 15.2373x; 1.0036x over previous
//
#include <hip/hip_runtime.h>
#include <hip/hip_bf16.h>
#include <math.h>

static constexpr int Bn = 4, Tlen = 2048, Cdim = 1024, Hn = 16, Dh = 64;
static constexpr int Mtot = Bn * Tlen;

typedef __attribute__((ext_vector_type(8)))  short    s16x8;
typedef __attribute__((ext_vector_type(4)))  float    f32x4;
typedef __attribute__((ext_vector_type(16))) float    f32x16;
typedef __attribute__((ext_vector_type(2)))  unsigned u32x2;
typedef unsigned short u16;

// scale folded into Q: (1/sqrt(64)) * log2(e)
#define QSCALE 0.18033688011112042f

__device__ __forceinline__ u16 f2bf(float f) {
    union { float f; unsigned u; } x; x.f = f;
    unsigned r = x.u + 0x7FFFu + ((x.u >> 16) & 1u);   // RNE
    return (u16)(r >> 16);
}
__device__ __forceinline__ unsigned cvtpk(float lo, float hi) {
    unsigned r;
    asm("v_cvt_pk_bf16_f32 %0, %1, %2" : "=v"(r) : "v"(lo), "v"(hi));
    return r;
}
__device__ __forceinline__ void gload_lds16(const void* g, void* l) {
    __builtin_amdgcn_global_load_lds(
        (const __attribute__((address_space(1))) void*)g,
        (__attribute__((address_space(3))) void*)l, 16, 0, 0);
}

// ---------------- fp32 -> bf16 convert (vectorized) ----------------
__global__ __launch_bounds__(256) void cvt_bf16(const float* __restrict__ in,
                                                u16* __restrict__ out) {
    size_t i = (size_t)(blockIdx.x * 256 + threadIdx.x) * 8;
    float4 a = *(const float4*)(in + i);
    float4 b = *(const float4*)(in + i + 4);
    s16x8 o;
    o[0] = (short)f2bf(a.x); o[1] = (short)f2bf(a.y);
    o[2] = (short)f2bf(a.z); o[3] = (short)f2bf(a.w);
    o[4] = (short)f2bf(b.x); o[5] = (short)f2bf(b.y);
    o[6] = (short)f2bf(b.z); o[7] = (short)f2bf(b.w);
    *(s16x8*)(out + i) = o;
}

// ---------------- fused QKV GEMM: A[8192,1024] x Wqkv[3072,1024]^T ----------------
// q plane scaled by QSCALE; v plane written TRANSPOSED to vt [B, H*D, T].
__global__ __launch_bounds__(256) void gemm_qkv(const u16* __restrict__ A,
                                                const u16* __restrict__ B,
                                                const float* __restrict__ bq,
                                                const float* __restrict__ bk,
                                                const float* __restrict__ bv,
                                                u16* __restrict__ qkbase,
                                                u16* __restrict__ vt) {
    constexpr int K = Cdim, N = Cdim;
    __shared__ u16 As[128 * 32];
    __shared__ u16 Bs[128 * 32];
    // bijective XCD swizzle: 1536 blocks = 8 * 192
    const int f = blockIdx.y * gridDim.x + blockIdx.x;
    const int f2 = (f & 7) * ((int)(gridDim.x * gridDim.y) >> 3) + (f >> 3);
    const int bxs = f2 & 63, bys = f2 >> 6;

    const int tid = threadIdx.x, lane = tid & 63, w = tid >> 6;
    const int m0 = bxs * 128, n0g = bys * 128;
    const int which = n0g >> 10, n0 = n0g & 1023;
    const float* bias = which == 0 ? bq : (which == 1 ? bk : bv);
    const float osc = which == 0 ? QSCALE : 1.0f;
    const int wm = w >> 1, wn = w & 1;
    const int rowA = lane & 15, kg = lane >> 4;
    const int srow = lane >> 2, sc4 = (lane & 3) * 8;

    f32x4 acc[4][4] = {};
    const u16* Abase = A + (size_t)m0 * K;
    const u16* Bbase = B + (size_t)n0g * K;

    for (int k0 = 0; k0 < K; k0 += 32) {
        __syncthreads();
#pragma unroll
        for (int i = 0; i < 2; ++i) {
            int r0 = w * 32 + i * 16;
            gload_lds16(Abase + (size_t)(r0 + srow) * K + k0 + sc4, As + r0 * 32);
            gload_lds16(Bbase + (size_t)(r0 + srow) * K + k0 + sc4, Bs + r0 * 32);
        }
        asm volatile("s_waitcnt vmcnt(0)" ::: "memory");
        __syncthreads();

        s16x8 af[4], bfr[4];
#pragma unroll
        for (int mf = 0; mf < 4; ++mf)
            af[mf] = *(const s16x8*)&As[(wm * 64 + mf * 16 + rowA) * 32 + kg * 8];
#pragma unroll
        for (int nf = 0; nf < 4; ++nf)
            bfr[nf] = *(const s16x8*)&Bs[(wn * 64 + nf * 16 + rowA) * 32 + kg * 8];
#pragma unroll
        for (int mf = 0; mf < 4; ++mf)
#pragma unroll
            for (int nf = 0; nf < 4; ++nf)
                acc[mf][nf] = __builtin_amdgcn_mfma_f32_16x16x32_bf16(
                    af[mf], bfr[nf], acc[mf][nf], 0, 0, 0);
    }

    float bb[4];
#pragma unroll
    for (int nf = 0; nf < 4; ++nf) bb[nf] = bias[n0 + wn * 64 + nf * 16 + rowA];

    if (which < 2) {
        u16* C = qkbase + (size_t)which * ((size_t)Mtot * Cdim);
#pragma unroll
        for (int mf = 0; mf < 4; ++mf)
#pragma unroll
            for (int nf = 0; nf < 4; ++nf)
#pragma unroll
                for (int r = 0; r < 4; ++r) {
                    float val = (acc[mf][nf][r] + bb[nf]) * osc;
                    size_t row = m0 + wm * 64 + mf * 16 + kg * 4 + r;
                    size_t col = n0 + wn * 64 + nf * 16 + rowA;
                    C[row * N + col] = f2bf(val);
                }
    } else {
        // V plane -> write transposed: vt[b*1024 + (h*64+d)][t], 4 consecutive t per frag
#pragma unroll
        for (int mf = 0; mf < 4; ++mf)
#pragma unroll
            for (int nf = 0; nf < 4; ++nf) {
                int hd = n0 + wn * 64 + nf * 16 + rowA;
                size_t row0 = m0 + wm * 64 + mf * 16 + kg * 4;
                int bi = (int)(row0 >> 11), t0 = (int)(row0 & 2047);
                union { u16 h[4]; u32x2 d; } pk;
#pragma unroll
                for (int r = 0; r < 4; ++r) pk.h[r] = f2bf(acc[mf][nf][r] + bb[nf]);
                *(u32x2*)(vt + ((size_t)bi * 1024 + hd) * Tlen + t0) = pk.d;
            }
    }
}

// ---------------- out-proj GEMM: bf16 A,B -> fp32 out ----------------
__global__ __launch_bounds__(256) void gemm_proj(const u16* __restrict__ A,
                                                 const u16* __restrict__ B,
                                                 const float* __restrict__ bias,
                                                 float* __restrict__ C) {
    constexpr int K = Cdim, N = Cdim;
    __shared__ u16 As[128 * 32];
    __shared__ u16 Bs[128 * 32];
    const int f = blockIdx.y * gridDim.x + blockIdx.x;    // 512 = 8 * 64
    const int f2 = (f & 7) * ((int)(gridDim.x * gridDim.y) >> 3) + (f >> 3);
    const int bxs = f2 & 63, bys = f2 >> 6;

    const int tid = threadIdx.x, lane = tid & 63, w = tid >> 6;
    const int m0 = bxs * 128, n0 = bys * 128;
    const int wm = w >> 1, wn = w & 1;
    const int rowA = lane & 15, kg = lane >> 4;
    const int srow = lane >> 2, sc4 = (lane & 3) * 8;

    f32x4 acc[4][4] = {};
    const u16* Abase = A + (size_t)m0 * K;
    const u16* Bbase = B + (size_t)n0 * K;

    for (int k0 = 0; k0 < K; k0 += 32) {
        __syncthreads();
#pragma unroll
        for (int i = 0; i < 2; ++i) {
            int r0 = w * 32 + i * 16;
            gload_lds16(Abase + (size_t)(r0 + srow) * K + k0 + sc4, As + r0 * 32);
            gload_lds16(Bbase + (size_t)(r0 + srow) * K + k0 + sc4, Bs + r0 * 32);
        }
        asm volatile("s_waitcnt vmcnt(0)" ::: "memory");
        __syncthreads();

        s16x8 af[4], bfr[4];
#pragma unroll
        for (int mf = 0; mf < 4; ++mf)
            af[mf] = *(const s16x8*)&As[(wm * 64 + mf * 16 + rowA) * 32 + kg * 8];
#pragma unroll
        for (int nf = 0; nf < 4; ++nf)
            bfr[nf] = *(const s16x8*)&Bs[(wn * 64 + nf * 16 + rowA) * 32 + kg * 8];
#pragma unroll
        for (int mf = 0; mf < 4; ++mf)
#pragma unroll
            for (int nf = 0; nf < 4; ++nf)
                acc[mf][nf] = __builtin_amdgcn_mfma_f32_16x16x32_bf16(
                    af[mf], bfr[nf], acc[mf][nf], 0, 0, 0);
    }

    float bb[4];
#pragma unroll
    for (int nf = 0; nf < 4; ++nf) bb[nf] = bias[n0 + wn * 64 + nf * 16 + rowA];
#pragma unroll
    for (int mf = 0; mf < 4; ++mf)
#pragma unroll
        for (int nf = 0; nf < 4; ++nf)
#pragma unroll
            for (int r = 0; r < 4; ++r) {
                size_t row = m0 + wm * 64 + mf * 16 + kg * 4 + r;
                size_t col = n0 + wn * 64 + nf * 16 + rowA;
                C[row * N + col] = acc[mf][nf][r] + bb[nf];
            }
}

// ---------------- MFMA flash attention, 32x32 swapped-operand ----------------
// 256 threads = 4 waves, 128 q-rows/block; wave w owns rows q0+w*32+[0,32).
// Flat 1024-block grid, LPT order (long qt first). Counted-vmcnt double buffer
// with raw s_barrier (no vmcnt(0) drain in steady state).
__global__ __launch_bounds__(256, 4) void attn_mfma(const u16* __restrict__ q,
                                                    const u16* __restrict__ k,
                                                    const u16* __restrict__ vt,
                                                    u16* y) {
    const int fid = blockIdx.x;
    const int qt = 15 - (fid >> 6);                 // LPT: qt=15 dispatched first
    const int rem = fid & 63;
    const int h = rem & 15, b = rem >> 4;
    const int tid = threadIdx.x, lane = tid & 63, w = tid >> 6;
    const int qlane = lane & 31, hi = lane >> 5;
    __shared__ u16 Ks[2][64 * 64];
    __shared__ u16 Vs[2][64 * 64];

    const int q0 = qt * 128;
    const int qrow_g = q0 + w * 32 + qlane;

    // Q fragments to registers: step s covers d = 16s + 8*hi + [0,8)
    const u16* qrow = q + ((size_t)(b * Tlen) + qrow_g) * Cdim + h * Dh;
    s16x8 qf[4];
#pragma unroll
    for (int s = 0; s < 4; ++s)
        qf[s] = *(const s16x8*)(qrow + s * 16 + hi * 8);

    const u16* kbase = k + ((size_t)(b * Tlen)) * Cdim + h * Dh;
    const u16* vbase = vt + ((size_t)(b * Hn + h)) * (size_t)(Dh * Tlen);

    // staging: thread stages granules tid and tid+256 of each 512-granule tile
    const int g0row = tid >> 3;
    const int g1row = g0row + 32;
    const int gc0 = (((tid) & 7) ^ (g0row & 7)) * 8;   // pre-swizzled source col
    const int gc1 = (((tid) & 7) ^ (g1row & 7)) * 8;

#define STAGE(JT, BUF)                                                              \
    do {                                                                            \
        const u16* kb2 = kbase + (size_t)((JT) * 64) * Cdim;                        \
        const u16* vb2 = vbase + (JT) * 64;                                         \
        gload_lds16(kb2 + (size_t)g0row * Cdim + gc0, &Ks[BUF][w * 512]);           \
        gload_lds16(kb2 + (size_t)g1row * Cdim + gc1, &Ks[BUF][2048 + w * 512]);    \
        gload_lds16(vb2 + (size_t)g0row * Tlen + gc0, &Vs[BUF][w * 512]);           \
        gload_lds16(vb2 + (size_t)g1row * Tlen + gc1, &Vs[BUF][2048 + w * 512]);    \
    } while (0)

    STAGE(0, 0);

    f32x16 o0, o1;
#pragma unroll
    for (int r = 0; r < 16; ++r) { o0[r] = 0.f; o1[r] = 0.f; }
    float m_i = -INFINITY, l_i = 0.f;

    const int njt = 2 * qt + 2;
    const int jtmax = 2 * qt + (w >> 1);          // last tile this wave needs
    const int swz = (qlane & 7);

    for (int jt = 0; jt < njt; ++jt) {
        const int cur = jt & 1;
        if (jt + 1 < njt) {
            STAGE(jt + 1, cur ^ 1);
            asm volatile("s_waitcnt vmcnt(4)" ::: "memory");   // cur landed, next in flight
        } else {
            asm volatile("s_waitcnt vmcnt(0)" ::: "memory");
        }
        __builtin_amdgcn_s_barrier();              // all waves' cur data visible

        if (jt <= jtmax) {
            const u16* kc = &Ks[cur][0];
            const u16* vc = &Vs[cur][0];
            // ---- S^T = K Q^T : two 32-kv subtiles
            f32x16 sA, sB;
#pragma unroll
            for (int r = 0; r < 16; ++r) { sA[r] = 0.f; sB[r] = 0.f; }
            __builtin_amdgcn_s_setprio(1);
#pragma unroll
            for (int s = 0; s < 4; ++s) {
                const int g8 = ((2 * s + hi) ^ swz) * 8;
                s16x8 k0 = *(const s16x8*)&kc[qlane * 64 + g8];
                s16x8 k1 = *(const s16x8*)&kc[(qlane + 32) * 64 + g8];
                sA = __builtin_amdgcn_mfma_f32_32x32x16_bf16(k0, qf[s], sA, 0, 0, 0);
                sB = __builtin_amdgcn_mfma_f32_32x32x16_bf16(k1, qf[s], sB, 0, 0, 0);
            }
            __builtin_amdgcn_s_setprio(0);

            // ---- causal mask (only near-diagonal tiles)
            if (jt * 64 + 63 > q0 + w * 32) {
#pragma unroll
                for (int r = 0; r < 16; ++r) {
                    int kv = jt * 64 + (r & 3) + 8 * (r >> 2) + 4 * hi;
                    if (kv > qrow_g)      sA[r] = -INFINITY;
                    if (kv + 32 > qrow_g) sB[r] = -INFINITY;
                }
            }
            // ---- online softmax, in-register (q = lane&31)
            float pm = -INFINITY;
#pragma unroll
            for (int r = 0; r < 16; ++r) pm = fmaxf(pm, fmaxf(sA[r], sB[r]));
            pm = fmaxf(pm, __shfl_xor(pm, 32));
            float nm = fmaxf(m_i, pm);
            float sc = exp2f(m_i - nm);
            m_i = nm;
            float ps = 0.f;
#pragma unroll
            for (int r = 0; r < 16; ++r) {
                sA[r] = exp2f(sA[r] - nm); ps += sA[r];
                sB[r] = exp2f(sB[r] - nm); ps += sB[r];
            }
            ps += __shfl_xor(ps, 32);
            l_i = l_i * sc + ps;
#pragma unroll
            for (int r = 0; r < 16; ++r) { o0[r] *= sc; o1[r] *= sc; }

            // ---- pack P (C/D layout) -> 4 MFMA B-frags via cvt_pk + shfl
            s16x8 pf[4];
            auto packsub = [&](const f32x16& sv, s16x8* out) {
#pragma unroll
                for (int t = 0; t < 2; ++t) {
                    unsigned X = cvtpk(sv[8 * t + 0], sv[8 * t + 1]);
                    unsigned Z = cvtpk(sv[8 * t + 2], sv[8 * t + 3]);
                    unsigned Y = cvtpk(sv[8 * t + 4], sv[8 * t + 5]);
                    unsigned W = cvtpk(sv[8 * t + 6], sv[8 * t + 7]);
                    unsigned U0 = hi ? Y : X, V0 = hi ? X : Y;
                    unsigned U1 = hi ? W : Z, V1 = hi ? Z : W;
                    unsigned S0 = (unsigned)__shfl_xor((int)V0, 32);
                    unsigned S1 = (unsigned)__shfl_xor((int)V1, 32);
                    union { unsigned u[4]; s16x8 v; } fr;
                    fr.u[0] = hi ? S0 : U0;
                    fr.u[1] = hi ? S1 : U1;
                    fr.u[2] = hi ? U0 : S0;
                    fr.u[3] = hi ? U1 : S1;
                    out[t] = fr.v;
                }
            };
            packsub(sA, pf);
            packsub(sB, pf + 2);

            // ---- O^T += V^T P^T : frag t covers kv = 16t + 8hi + [0,8)
            __builtin_amdgcn_s_setprio(1);
#pragma unroll
            for (int t = 0; t < 4; ++t) {
                const int g8 = ((2 * t + hi) ^ swz) * 8;
                s16x8 v0 = *(const s16x8*)&vc[qlane * 64 + g8];
                s16x8 v1 = *(const s16x8*)&vc[(qlane + 32) * 64 + g8];
                o0 = __builtin_amdgcn_mfma_f32_32x32x16_bf16(v0, pf[t], o0, 0, 0, 0);
                o1 = __builtin_amdgcn_mfma_f32_32x32x16_bf16(v1, pf[t], o1, 0, 0, 0);
            }
            __builtin_amdgcn_s_setprio(0);
        }
        asm volatile("" ::: "memory");
        __builtin_amdgcn_s_barrier();              // all waves done reading cur
    }
#undef STAGE

    // ---- normalize + write: lane owns q-row qrow_g; d = (r&3)+8*(r>>2)+4hi(+32)
    float inv = 1.f / l_i;
    u16* yrow = y + ((size_t)(b * Tlen) + qrow_g) * Cdim + h * Dh;
#pragma unroll
    for (int g2 = 0; g2 < 4; ++g2) {
        u32x2 st;
        st[0] = cvtpk(o0[4 * g2 + 0] * inv, o0[4 * g2 + 1] * inv);
        st[1] = cvtpk(o0[4 * g2 + 2] * inv, o0[4 * g2 + 3] * inv);
        *(u32x2*)(yrow + 8 * g2 + 4 * hi) = st;
        st[0] = cvtpk(o1[4 * g2 + 0] * inv, o1[4 * g2 + 1] * inv);
        st[1] = cvtpk(o1[4 * g2 + 2] * inv, o1[4 * g2 + 3] * inv);
        *(u32x2*)(yrow + 32 + 8 * g2 + 4 * hi) = st;
    }
}

extern "C" void kernel_launch(void* const* d_in, const int* in_sizes, int n_in,
                              void* d_out, int out_size, void* d_ws, size_t ws_size,
                              hipStream_t stream) {
    const float* x  = (const float*)d_in[0];
    const float* Wq = (const float*)d_in[1];
    const float* bq = (const float*)d_in[2];
    const float* Wk = (const float*)d_in[3];
    const float* bk = (const float*)d_in[4];
    const float* Wv = (const float*)d_in[5];
    const float* bv = (const float*)d_in[6];
    const float* Wp = (const float*)d_in[7];
    const float* bp = (const float*)d_in[8];
    float* out = (float*)d_out;

    const size_t plane = (size_t)Mtot * Cdim;   // 8M elems
    const size_t wsz   = (size_t)Cdim * Cdim;   // 1M elems
    u16* xb    = (u16*)d_ws;
    u16* wqkvb = xb + plane;                    // Wq|Wk|Wv
    u16* wpb   = wqkvb + 3 * wsz;
    u16* qb    = wpb + wsz;                     // q,k planes contiguous
    u16* kb    = qb + plane;
    u16* vtb   = kb + plane;                    // V^T plane [B][H*D][T]

    cvt_bf16<<<plane / 2048, 256, 0, stream>>>(x, xb);
    cvt_bf16<<<wsz / 2048, 256, 0, stream>>>(Wq, wqkvb);
    cvt_bf16<<<wsz / 2048, 256, 0, stream>>>(Wk, wqkvb + wsz);
    cvt_bf16<<<wsz / 2048, 256, 0, stream>>>(Wv, wqkvb + 2 * wsz);
    cvt_bf16<<<wsz / 2048, 256, 0, stream>>>(Wp, wpb);

    gemm_qkv<<<dim3(Mtot / 128, 3 * Cdim / 128), 256, 0, stream>>>(
        xb, wqkvb, bq, bk, bv, qb, vtb);

    attn_mfma<<<dim3(1024), 256, 0, stream>>>(qb, kb, vtb, qb);

    gemm_proj<<<dim3(Mtot / 128, Cdim / 128), 256, 0, stream>>>(qb, wpb, bp, out);
}

// Round 9
// 183.070 us; speedup vs baseline: 17.6614x; 1.1591x over previous
//
#include <hip/hip_runtime.h>
#include <hip/hip_bf16.h>
#include <math.h>

static constexpr int Bn = 4, Tlen = 2048, Cdim = 1024, Hn = 16, Dh = 64;
static constexpr int Mtot = Bn * Tlen;

typedef __attribute__((ext_vector_type(8)))  short    s16x8;
typedef __attribute__((ext_vector_type(4)))  float    f32x4;
typedef __attribute__((ext_vector_type(16))) float    f32x16;
typedef __attribute__((ext_vector_type(2)))  unsigned u32x2;
typedef unsigned short u16;

// scale folded into Q: (1/sqrt(64)) * log2(e)
#define QSCALE 0.18033688011112042f

__device__ __forceinline__ u16 f2bf(float f) {
    union { float f; unsigned u; } x; x.f = f;
    unsigned r = x.u + 0x7FFFu + ((x.u >> 16) & 1u);   // RNE
    return (u16)(r >> 16);
}
__device__ __forceinline__ unsigned cvtpk(float lo, float hi) {
    unsigned r;
    asm("v_cvt_pk_bf16_f32 %0, %1, %2" : "=v"(r) : "v"(lo), "v"(hi));
    return r;
}
__device__ __forceinline__ void gload_lds16(const void* g, void* l) {
    __builtin_amdgcn_global_load_lds(
        (const __attribute__((address_space(1))) void*)g,
        (__attribute__((address_space(3))) void*)l, 16, 0, 0);
}

// ---------------- fp32 -> bf16 convert (vectorized) ----------------
__global__ __launch_bounds__(256) void cvt_bf16(const float* __restrict__ in,
                                                u16* __restrict__ out) {
    size_t i = (size_t)(blockIdx.x * 256 + threadIdx.x) * 8;
    float4 a = *(const float4*)(in + i);
    float4 b = *(const float4*)(in + i + 4);
    s16x8 o;
    o[0] = (short)f2bf(a.x); o[1] = (short)f2bf(a.y);
    o[2] = (short)f2bf(a.z); o[3] = (short)f2bf(a.w);
    o[4] = (short)f2bf(b.x); o[5] = (short)f2bf(b.y);
    o[6] = (short)f2bf(b.z); o[7] = (short)f2bf(b.w);
    *(s16x8*)(out + i) = o;
}

// ---------------- 8-wave NT GEMM: BM=128, BN=256, BK=32 ----------------
// 3-buffer rotation, prefetch distance 2, counted vmcnt(3) per K-tile
// (never drains in steady state). Granule-XOR swizzle on LDS (both sides).
// MODE 0: proj -> fp32 C[M,1024] (+bias bq);  MODE 1: qkv -> q(xQSCALE),k bf16
// planes at out0, v written transposed into vt [B, H*D, T].
template <int MODE, int NB>
__global__ __launch_bounds__(512, 4) void gemm8w(const u16* __restrict__ A,
                                                 const u16* __restrict__ Bm,
                                                 const float* __restrict__ bq,
                                                 const float* __restrict__ bk,
                                                 const float* __restrict__ bv,
                                                 void* __restrict__ out0,
                                                 u16* __restrict__ vt) {
    constexpr int K = Cdim;
    constexpr int NKT = K / 32;                 // 32 K-tiles
    __shared__ u16 As[3][128 * 32];             // 24 KB
    __shared__ u16 Bs[3][256 * 32];             // 48 KB

    // bijective XCD swizzle (grid = 64*NB, divisible by 8)
    const int f  = blockIdx.x;
    const int f2 = (f & 7) * (8 * NB) + (f >> 3);
    const int bm = f2 / NB, bn = f2 % NB;
    const int m0 = bm * 128, n0g = bn * 256;

    const int tid = threadIdx.x, lane = tid & 63, w = tid >> 6;
    const int wm = w >> 2, wn = w & 3;          // 2M x 4N waves
    const int rowA = lane & 15, kg = lane >> 4;

    // ---- staging geometry: per K-tile, thread does 1 A-load + 2 B-loads ----
    const int srow  = w * 16 + (lane >> 2);              // 0..127
    const int scolA = (((lane & 3) ^ (srow & 3)) * 8);   // pre-swizzled source granule
    const u16* Ab  = A  + (size_t)(m0 + srow) * K + scolA;
    const u16* Bb0 = Bm + (size_t)(n0g + srow) * K + scolA;
    const u16* Bb1 = Bm + (size_t)(n0g + 128 + srow) * K + scolA;

#define STAGE_T(KT, BUF)                                              \
    do {                                                              \
        const int k0_ = (KT) * 32;                                    \
        gload_lds16(Ab  + k0_, &As[BUF][w * 512]);                    \
        gload_lds16(Bb0 + k0_, &Bs[BUF][w * 512]);                    \
        gload_lds16(Bb1 + k0_, &Bs[BUF][4096 + w * 512]);             \
    } while (0)

    // ---- fragment read offsets (swizzled granule; row&3 == rowA&3) ----
    const int fswz = ((kg ^ (rowA & 3)) * 8);
    const int aoff = (wm * 64 + rowA) * 32 + fswz;   // + mf*512
    const int boff = (wn * 64 + rowA) * 32 + fswz;   // + nf*512

    f32x4 acc[4][4] = {};

    STAGE_T(0, 0);
    STAGE_T(1, 1);
    asm volatile("s_waitcnt vmcnt(3)" ::: "memory");   // tile 0 landed
    __builtin_amdgcn_s_barrier();

    for (int kt = 0; kt < NKT; ++kt) {
        const int cur = kt % 3;
        s16x8 af[4], bf[4];
#pragma unroll
        for (int i = 0; i < 4; ++i) {
            af[i] = *(const s16x8*)&As[cur][aoff + i * 512];
            bf[i] = *(const s16x8*)&Bs[cur][boff + i * 512];
        }
        if (kt + 2 < NKT) STAGE_T(kt + 2, (kt + 2) % 3);   // write buf != any read buf
        __builtin_amdgcn_s_barrier();

        __builtin_amdgcn_s_setprio(1);
#pragma unroll
        for (int mf = 0; mf < 4; ++mf)
#pragma unroll
            for (int nf = 0; nf < 4; ++nf)
                acc[mf][nf] = __builtin_amdgcn_mfma_f32_16x16x32_bf16(
                    af[mf], bf[nf], acc[mf][nf], 0, 0, 0);
        __builtin_amdgcn_s_setprio(0);

        if (kt + 2 < NKT) asm volatile("s_waitcnt vmcnt(3)" ::: "memory"); // kt+1 landed
        else              asm volatile("s_waitcnt vmcnt(0)" ::: "memory");
        __builtin_amdgcn_s_barrier();
    }
#undef STAGE_T

    // ---- epilogue ----
    const int which = (MODE == 1) ? (n0g >> 10) : 0;
    const int n0 = n0g & 1023;
    const float* bias = (MODE == 0) ? bq : (which == 0 ? bq : (which == 1 ? bk : bv));
    const float osc = (MODE == 1 && which == 0) ? QSCALE : 1.0f;
    float bb[4];
#pragma unroll
    for (int nf = 0; nf < 4; ++nf) bb[nf] = bias[n0 + wn * 64 + nf * 16 + rowA];

    if (MODE == 0) {
        float* C = (float*)out0;
#pragma unroll
        for (int mf = 0; mf < 4; ++mf)
#pragma unroll
            for (int nf = 0; nf < 4; ++nf)
#pragma unroll
                for (int r = 0; r < 4; ++r) {
                    size_t row = m0 + wm * 64 + mf * 16 + kg * 4 + r;
                    size_t col = n0 + wn * 64 + nf * 16 + rowA;
                    C[row * 1024 + col] = acc[mf][nf][r] + bb[nf];
                }
    } else if (which < 2) {
        u16* C = (u16*)out0 + (size_t)which * ((size_t)Mtot * Cdim);
#pragma unroll
        for (int mf = 0; mf < 4; ++mf)
#pragma unroll
            for (int nf = 0; nf < 4; ++nf)
#pragma unroll
                for (int r = 0; r < 4; ++r) {
                    float val = (acc[mf][nf][r] + bb[nf]) * osc;
                    size_t row = m0 + wm * 64 + mf * 16 + kg * 4 + r;
                    size_t col = n0 + wn * 64 + nf * 16 + rowA;
                    C[row * 1024 + col] = f2bf(val);
                }
    } else {
        // V plane -> transposed: vt[b*1024 + hd][t], 4 consecutive t per frag
#pragma unroll
        for (int mf = 0; mf < 4; ++mf)
#pragma unroll
            for (int nf = 0; nf < 4; ++nf) {
                int hd = n0 + wn * 64 + nf * 16 + rowA;
                size_t row0 = m0 + wm * 64 + mf * 16 + kg * 4;
                int bi = (int)(row0 >> 11), t0 = (int)(row0 & 2047);
                union { u16 h[4]; u32x2 d; } pk;
#pragma unroll
                for (int r = 0; r < 4; ++r) pk.h[r] = f2bf(acc[mf][nf][r] + bb[nf]);
                *(u32x2*)(vt + ((size_t)bi * 1024 + hd) * Tlen + t0) = pk.d;
            }
    }
}

// ---------------- MFMA flash attention, 32x32 swapped-operand ----------------
// 256 threads = 4 waves, 128 q-rows/block; wave w owns rows q0+w*32+[0,32).
// Flat 1024-block grid, LPT order. Counted-vmcnt double buffer + defer-max.
__global__ __launch_bounds__(256, 4) void attn_mfma(const u16* __restrict__ q,
                                                    const u16* __restrict__ k,
                                                    const u16* __restrict__ vt,
                                                    u16* y) {
    const int fid = blockIdx.x;
    const int qt = 15 - (fid >> 6);                 // LPT: qt=15 dispatched first
    const int rem = fid & 63;
    const int h = rem & 15, b = rem >> 4;
    const int tid = threadIdx.x, lane = tid & 63, w = tid >> 6;
    const int qlane = lane & 31, hi = lane >> 5;
    __shared__ u16 Ks[2][64 * 64];
    __shared__ u16 Vs[2][64 * 64];

    const int q0 = qt * 128;
    const int qrow_g = q0 + w * 32 + qlane;

    // Q fragments to registers: step s covers d = 16s + 8*hi + [0,8)
    const u16* qrow = q + ((size_t)(b * Tlen) + qrow_g) * Cdim + h * Dh;
    s16x8 qf[4];
#pragma unroll
    for (int s = 0; s < 4; ++s)
        qf[s] = *(const s16x8*)(qrow + s * 16 + hi * 8);

    const u16* kbase = k + ((size_t)(b * Tlen)) * Cdim + h * Dh;
    const u16* vbase = vt + ((size_t)(b * Hn + h)) * (size_t)(Dh * Tlen);

    // staging: thread stages granules tid and tid+256 of each 512-granule tile
    const int g0row = tid >> 3;
    const int g1row = g0row + 32;
    const int gc0 = (((tid) & 7) ^ (g0row & 7)) * 8;   // pre-swizzled source col
    const int gc1 = (((tid) & 7) ^ (g1row & 7)) * 8;

#define STAGE(JT, BUF)                                                              \
    do {                                                                            \
        const u16* kb2 = kbase + (size_t)((JT) * 64) * Cdim;                        \
        const u16* vb2 = vbase + (JT) * 64;                                         \
        gload_lds16(kb2 + (size_t)g0row * Cdim + gc0, &Ks[BUF][w * 512]);           \
        gload_lds16(kb2 + (size_t)g1row * Cdim + gc1, &Ks[BUF][2048 + w * 512]);    \
        gload_lds16(vb2 + (size_t)g0row * Tlen + gc0, &Vs[BUF][w * 512]);           \
        gload_lds16(vb2 + (size_t)g1row * Tlen + gc1, &Vs[BUF][2048 + w * 512]);    \
    } while (0)

    STAGE(0, 0);

    f32x16 o0, o1;
#pragma unroll
    for (int r = 0; r < 16; ++r) { o0[r] = 0.f; o1[r] = 0.f; }
    float m_i = -INFINITY, l_i = 0.f;

    const int njt = 2 * qt + 2;
    const int jtmax = 2 * qt + (w >> 1);          // last tile this wave needs
    const int swz = (qlane & 7);

    for (int jt = 0; jt < njt; ++jt) {
        const int cur = jt & 1;
        if (jt + 1 < njt) {
            STAGE(jt + 1, cur ^ 1);
            asm volatile("s_waitcnt vmcnt(4)" ::: "memory");   // cur landed, next in flight
        } else {
            asm volatile("s_waitcnt vmcnt(0)" ::: "memory");
        }
        __builtin_amdgcn_s_barrier();              // all waves' cur data visible

        if (jt <= jtmax) {
            const u16* kc = &Ks[cur][0];
            const u16* vc = &Vs[cur][0];
            // ---- S^T = K Q^T : two 32-kv subtiles
            f32x16 sA, sB;
#pragma unroll
            for (int r = 0; r < 16; ++r) { sA[r] = 0.f; sB[r] = 0.f; }
            __builtin_amdgcn_s_setprio(1);
#pragma unroll
            for (int s = 0; s < 4; ++s) {
                const int g8 = ((2 * s + hi) ^ swz) * 8;
                s16x8 k0 = *(const s16x8*)&kc[qlane * 64 + g8];
                s16x8 k1 = *(const s16x8*)&kc[(qlane + 32) * 64 + g8];
                sA = __builtin_amdgcn_mfma_f32_32x32x16_bf16(k0, qf[s], sA, 0, 0, 0);
                sB = __builtin_amdgcn_mfma_f32_32x32x16_bf16(k1, qf[s], sB, 0, 0, 0);
            }
            __builtin_amdgcn_s_setprio(0);

            // ---- causal mask (only near-diagonal tiles)
            if (jt * 64 + 63 > q0 + w * 32) {
#pragma unroll
                for (int r = 0; r < 16; ++r) {
                    int kv = jt * 64 + (r & 3) + 8 * (r >> 2) + 4 * hi;
                    if (kv > qrow_g)      sA[r] = -INFINITY;
                    if (kv + 32 > qrow_g) sB[r] = -INFINITY;
                }
            }
            // ---- online softmax with defer-max (T13): skip rescale if max
            // growth <= 8 (log2 domain); P bounded by 2^8, f32 accum fine.
            float pm = -INFINITY;
#pragma unroll
            for (int r = 0; r < 16; ++r) pm = fmaxf(pm, fmaxf(sA[r], sB[r]));
            pm = fmaxf(pm, __shfl_xor(pm, 32));
            const bool skip = (bool)__all(pm <= m_i + 8.0f);
            float nm = m_i, sc = 1.0f;
            if (!skip) {
                nm = fmaxf(m_i, pm);
                sc = exp2f(m_i - nm);
                m_i = nm;
            }
            float ps = 0.f;
#pragma unroll
            for (int r = 0; r < 16; ++r) {
                sA[r] = exp2f(sA[r] - nm); ps += sA[r];
                sB[r] = exp2f(sB[r] - nm); ps += sB[r];
            }
            ps += __shfl_xor(ps, 32);
            if (!skip) {
                l_i = l_i * sc + ps;
#pragma unroll
                for (int r = 0; r < 16; ++r) { o0[r] *= sc; o1[r] *= sc; }
            } else {
                l_i += ps;
            }

            // ---- pack P (C/D layout) -> 4 MFMA B-frags via cvt_pk + shfl
            s16x8 pf[4];
            auto packsub = [&](const f32x16& sv, s16x8* out) {
#pragma unroll
                for (int t = 0; t < 2; ++t) {
                    unsigned X = cvtpk(sv[8 * t + 0], sv[8 * t + 1]);
                    unsigned Z = cvtpk(sv[8 * t + 2], sv[8 * t + 3]);
                    unsigned Y = cvtpk(sv[8 * t + 4], sv[8 * t + 5]);
                    unsigned W = cvtpk(sv[8 * t + 6], sv[8 * t + 7]);
                    unsigned U0 = hi ? Y : X, V0 = hi ? X : Y;
                    unsigned U1 = hi ? W : Z, V1 = hi ? Z : W;
                    unsigned S0 = (unsigned)__shfl_xor((int)V0, 32);
                    unsigned S1 = (unsigned)__shfl_xor((int)V1, 32);
                    union { unsigned u[4]; s16x8 v; } fr;
                    fr.u[0] = hi ? S0 : U0;
                    fr.u[1] = hi ? S1 : U1;
                    fr.u[2] = hi ? U0 : S0;
                    fr.u[3] = hi ? U1 : S1;
                    out[t] = fr.v;
                }
            };
            packsub(sA, pf);
            packsub(sB, pf + 2);

            // ---- O^T += V^T P^T : frag t covers kv = 16t + 8hi + [0,8)
            __builtin_amdgcn_s_setprio(1);
#pragma unroll
            for (int t = 0; t < 4; ++t) {
                const int g8 = ((2 * t + hi) ^ swz) * 8;
                s16x8 v0 = *(const s16x8*)&vc[qlane * 64 + g8];
                s16x8 v1 = *(const s16x8*)&vc[(qlane + 32) * 64 + g8];
                o0 = __builtin_amdgcn_mfma_f32_32x32x16_bf16(v0, pf[t], o0, 0, 0, 0);
                o1 = __builtin_amdgcn_mfma_f32_32x32x16_bf16(v1, pf[t], o1, 0, 0, 0);
            }
            __builtin_amdgcn_s_setprio(0);
        }
        asm volatile("" ::: "memory");
        __builtin_amdgcn_s_barrier();              // all waves done reading cur
    }
#undef STAGE

    // ---- normalize + write: lane owns q-row qrow_g; d = (r&3)+8*(r>>2)+4hi(+32)
    float inv = 1.f / l_i;
    u16* yrow = y + ((size_t)(b * Tlen) + qrow_g) * Cdim + h * Dh;
#pragma unroll
    for (int g2 = 0; g2 < 4; ++g2) {
        u32x2 st;
        st[0] = cvtpk(o0[4 * g2 + 0] * inv, o0[4 * g2 + 1] * inv);
        st[1] = cvtpk(o0[4 * g2 + 2] * inv, o0[4 * g2 + 3] * inv);
        *(u32x2*)(yrow + 8 * g2 + 4 * hi) = st;
        st[0] = cvtpk(o1[4 * g2 + 0] * inv, o1[4 * g2 + 1] * inv);
        st[1] = cvtpk(o1[4 * g2 + 2] * inv, o1[4 * g2 + 3] * inv);
        *(u32x2*)(yrow + 32 + 8 * g2 + 4 * hi) = st;
    }
}

extern "C" void kernel_launch(void* const* d_in, const int* in_sizes, int n_in,
                              void* d_out, int out_size, void* d_ws, size_t ws_size,
                              hipStream_t stream) {
    const float* x  = (const float*)d_in[0];
    const float* Wq = (const float*)d_in[1];
    const float* bq = (const float*)d_in[2];
    const float* Wk = (const float*)d_in[3];
    const float* bk = (const float*)d_in[4];
    const float* Wv = (const float*)d_in[5];
    const float* bv = (const float*)d_in[6];
    const float* Wp = (const float*)d_in[7];
    const float* bp = (const float*)d_in[8];
    float* out = (float*)d_out;

    const size_t plane = (size_t)Mtot * Cdim;   // 8M elems
    const size_t wsz   = (size_t)Cdim * Cdim;   // 1M elems
    u16* xb    = (u16*)d_ws;
    u16* wqkvb = xb + plane;                    // Wq|Wk|Wv
    u16* wpb   = wqkvb + 3 * wsz;
    u16* qb    = wpb + wsz;                     // q,k planes contiguous
    u16* kb    = qb + plane;
    u16* vtb   = kb + plane;                    // V^T plane [B][H*D][T]

    cvt_bf16<<<plane / 2048, 256, 0, stream>>>(x, xb);
    cvt_bf16<<<wsz / 2048, 256, 0, stream>>>(Wq, wqkvb);
    cvt_bf16<<<wsz / 2048, 256, 0, stream>>>(Wk, wqkvb + wsz);
    cvt_bf16<<<wsz / 2048, 256, 0, stream>>>(Wv, wqkvb + 2 * wsz);
    cvt_bf16<<<wsz / 2048, 256, 0, stream>>>(Wp, wpb);

    // QKV: M=8192, N=3072 -> 64 x 12 = 768 blocks (3 balanced rounds)
    gemm8w<1, 12><<<dim3(768), 512, 0, stream>>>(xb, wqkvb, bq, bk, bv, qb, vtb);

    attn_mfma<<<dim3(1024), 256, 0, stream>>>(qb, kb, vtb, qb);

    // proj: M=8192, N=1024 -> 64 x 4 = 256 blocks (1 balanced round)
    gemm8w<0, 4><<<dim3(256), 512, 0, stream>>>(qb, wpb, bp, bp, bp, out, nullptr);
}